// Round 7
// baseline (471.115 us; speedup 1.0000x reference)
//
#include <hip/hip_runtime.h>
#include <math.h>
#include <string.h>

#define BATCH 8
#define CH 512
#define LEN 2048
#define NG 32
#define CPG 16

typedef unsigned short u16;
typedef __bf16 bf16x8 __attribute__((ext_vector_type(8)));
typedef float f32x16 __attribute__((ext_vector_type(16)));
typedef float f32x4v __attribute__((ext_vector_type(4)));

__device__ __forceinline__ u16 f2bf(float f) {
    union { float f; unsigned u; } c; c.f = f;
    unsigned r = c.u + 0x7fffu + ((c.u >> 16) & 1u);   // RNE
    return (u16)(r >> 16);
}
__device__ __forceinline__ float bf2f(u16 h) {
    union { unsigned u; float f; } c; c.u = ((unsigned)h) << 16;
    return c.f;
}
__device__ __forceinline__ void gload16(const u16* g, u16* l) {
    __builtin_amdgcn_global_load_lds(
        (const __attribute__((address_space(1))) unsigned int*)g,
        (__attribute__((address_space(3))) unsigned int*)l, 16, 0, 0);
}
// nontemporal 8B store of a ushort4 (streaming outputs: skip L2 retention)
__device__ __forceinline__ void nt_store_u4(ushort4 v, u16* p) {
    union { ushort4 s; unsigned long long u; } cv; cv.s = v;
    __builtin_nontemporal_store(cv.u, (unsigned long long*)p);
}

// ---------------------------------------------------------------------------
__global__ __launch_bounds__(256) void zerof4(float4* __restrict__ p) {
    p[blockIdx.x * 256 + threadIdx.x] = make_float4(0.f, 0.f, 0.f, 0.f);
}

// ---------------------------------------------------------------------------
__global__ __launch_bounds__(256) void wconv4(const float* __restrict__ w0, const float* __restrict__ w1,
                                              const float* __restrict__ w2, const float* __restrict__ w3,
                                              u16* __restrict__ o0, u16* __restrict__ o1,
                                              u16* __restrict__ o2, u16* __restrict__ o3) {
    const float* s; u16* d;
    switch (blockIdx.y) {
        case 0: s = w0; d = o0; break;
        case 1: s = w1; d = o1; break;
        case 2: s = w2; d = o2; break;
        default: s = w3; d = o3; break;
    }
    const int i = blockIdx.x * 256 + threadIdx.x;
    float4 f = ((const float4*)s)[i];
    ushort4 o = make_ushort4(f2bf(f.x), f2bf(f.y), f2bf(f.z), f2bf(f.w));
    ((ushort4*)d)[i] = o;
}

// ---------------------------------------------------------------------------
__global__ __launch_bounds__(256) void gn_stats(const float* __restrict__ x,
                                                const float* __restrict__ gw,
                                                const float* __restrict__ gb,
                                                float* __restrict__ gnA,
                                                float* __restrict__ gnB) {
    const int b = blockIdx.x >> 5, g = blockIdx.x & 31;
    const float4* xp = (const float4*)(x + ((size_t)b * CH + (size_t)g * CPG) * LEN);
    float s = 0.f, s2 = 0.f;
    for (int i = threadIdx.x; i < (CPG * LEN) / 4; i += 256) {
        float4 v = xp[i];
        s += v.x + v.y + v.z + v.w;
        s2 = fmaf(v.x, v.x, fmaf(v.y, v.y, fmaf(v.z, v.z, fmaf(v.w, v.w, s2))));
    }
    #pragma unroll
    for (int off = 32; off > 0; off >>= 1) {
        s  += __shfl_down(s, off, 64);
        s2 += __shfl_down(s2, off, 64);
    }
    __shared__ float sm[2][4];
    const int lane = threadIdx.x & 63, wv = threadIdx.x >> 6;
    if (lane == 0) { sm[0][wv] = s; sm[1][wv] = s2; }
    __syncthreads();
    if (threadIdx.x < CPG) {
        const float S  = sm[0][0] + sm[0][1] + sm[0][2] + sm[0][3];
        const float S2 = sm[1][0] + sm[1][1] + sm[1][2] + sm[1][3];
        const float mean = S * (1.f / (CPG * LEN));
        const float var  = S2 * (1.f / (CPG * LEN)) - mean * mean;
        const float rstd = rsqrtf(var + 1e-6f);
        const int c = g * CPG + threadIdx.x;
        const float sc = rstd * gw[c];
        gnA[b * CH + c] = sc;
        gnB[b * CH + c] = gb[c] - mean * sc;
    }
}

// ---------------------------------------------------------------------------
__global__ __launch_bounds__(256) void gn_apply_t(const float* __restrict__ x,
                                                  const float* __restrict__ gnA,
                                                  const float* __restrict__ gnB,
                                                  u16* __restrict__ Ht) {
    __shared__ float tile[64][65];
    const int b = blockIdx.z, c0 = blockIdx.y * 64, l0 = blockIdx.x * 64;
    const int t = threadIdx.x, tl = t & 63, tr = t >> 6;
    #pragma unroll 4
    for (int i = 0; i < 16; ++i) {
        const int c = tr + i * 4;
        const float a = gnA[b * CH + c0 + c];
        const float sh = gnB[b * CH + c0 + c];
        tile[c][tl] = x[((size_t)b * CH + c0 + c) * LEN + l0 + tl] * a + sh;
    }
    __syncthreads();
    #pragma unroll 4
    for (int i = 0; i < 16; ++i) {
        const int l = tr + i * 4;
        Ht[((size_t)b * LEN + l0 + l) * CH + c0 + tl] = f2bf(tile[tl][l]);
    }
}

// ---------------------------------------------------------------------------
// MFMA GEMM (B^T form), 128x128 tile, BK=64, mfma_f32_32x32x16_bf16.
// r4 schedule (proven best: single-buffer, 2-barrier, 256 thr / 4 waves,
// 4 blocks/CU via __launch_bounds__(256,4)) + round-7 memory-system fixes:
//  (1) bijective XCD remap: each XCD gets a contiguous chunk of flat tile
//      space (here: whole batches), so its 4MB L2 holds ONE batch's panels
//      instead of an interleave of all 8 (r4 had no remap -> 2.2x overfetch).
//  (2) PV (EPI_TNRM) uses m-fast (c-fast) in-XCD order: 4 consecutive blocks
//      share one Sb i-panel (512KB) with all of Vb (2MB) L2-resident ->
//      Sb fetched once instead of ~4x (was re-streamed per c-tile).
//  (3) nontemporal stores for streaming outputs (Sb in EPI_EXP, f32 out in
//      EPI_FIN) + nt-load of the residual: stops 67MB write streams from
//      evicting the resident Qt/Kt panels.
// LDS k-chunks XOR-swizzled by row (chunk stored at c = kc ^ (row&7)) via the
// GLOBAL source address (global_load_lds dest must stay lane-contiguous).
// ---------------------------------------------------------------------------
#define EPI_QK   0   // bf16; (Out,bias)/(Out2,bias2) by m half; +bias[m]
#define EPI_TBN  1   // bf16; +bias[n]
#define EPI_EXP  2   // bf16; exp(acc*alpha), accumulate rowsum[n]; nt-store
#define EPI_TNRM 3   // bf16; * (1/rowsum[n]); m-fast block order
#define EPI_FIN  4   // f32;  +bias[n] + res; nt-store out, nt-load res

template <int MODE>
__global__ __launch_bounds__(256, 4) void gemm_bt(
    const u16* __restrict__ A, int lda, long long sA,
    const u16* __restrict__ B, int ldb, long long sB,
    void* __restrict__ Out, void* __restrict__ Out2,
    int ldo, long long sO,
    const float* __restrict__ bias, const float* __restrict__ bias2,
    const float* __restrict__ res, long long sR,
    float* __restrict__ rsum, long long sRS,
    int K, float alpha) {
    __shared__ u16 As[128 * 64];   // 16 KB
    __shared__ u16 Bs[128 * 64];   // 16 KB

    // ---- bijective XCD remap (all grids have nbk % 8 == 0)
    const int gx = gridDim.x, gy = gridDim.y;
    int flat = (blockIdx.z * gy + blockIdx.y) * gx + blockIdx.x;
    const int nbk = gx * gy * (int)gridDim.z;
    flat = (flat & 7) * (nbk >> 3) + (flat >> 3);
    const int bz = flat / (gx * gy);
    const int rr = flat - bz * gx * gy;
    int by, bx;
    if (MODE == EPI_TNRM) {   // m(c)-fast: share Sb i-panels, Vb L2-resident
        by = rr % gy; bx = rr / gy;
    } else {                  // n-fast: A-panel fixed, B batch L2-resident
        by = rr / gx; bx = rr % gx;
    }

    const int n0 = bx * 128, m0 = by * 128;
    A += (size_t)bz * sA;
    B += (size_t)bz * sB;
    const int t = threadIdx.x;
    const int lane = t & 63, wid = t >> 6;

    // staging: thread t owns LDS slots (row = t>>3 + g*32, chunk = t&7);
    // source chunk is XOR-swizzled: global chunk = (t&7) ^ (row&7)
    const int rowL = t >> 3, kq = (t & 7) ^ (rowL & 7);
    unsigned aoff = (unsigned)((m0 + rowL) * lda + kq * 8);
    unsigned boff = (unsigned)((n0 + rowL) * ldb + kq * 8);
    u16* const lds_dst_a = As + t * 8;
    u16* const lds_dst_b = Bs + t * 8;

    f32x16 acc[2][2];
    #pragma unroll
    for (int i = 0; i < 2; ++i)
        #pragma unroll
        for (int j = 0; j < 2; ++j)
            acc[i][j] = (f32x16)(0.f);

    const int col = lane & 31, half = lane >> 5;
    const int wm = (wid & 1) * 64, wn = (wid >> 1) * 64;
    const int mf = wm + col, nf = wn + col;
    const int mswz = mf & 7, nswz = nf & 7;   // row-invariant mod 8 for +32 rows

    for (int k0 = 0; k0 < K; k0 += 64) {
        #pragma unroll
        for (int g = 0; g < 4; ++g) {
            gload16(A + aoff + g * (32 * lda), lds_dst_a + g * 2048);
            gload16(B + boff + g * (32 * ldb), lds_dst_b + g * 2048);
        }
        aoff += 64; boff += 64;
        __syncthreads();
        #pragma unroll
        for (int ks = 0; ks < 4; ++ks) {
            const int kcA = ((ks * 2 + half) ^ mswz) * 8;
            const int kcB = ((ks * 2 + half) ^ nswz) * 8;
            bf16x8 a0 = *(const bf16x8*)(As + (mf)      * 64 + kcA);
            bf16x8 a1 = *(const bf16x8*)(As + (mf + 32) * 64 + kcA);
            bf16x8 b0 = *(const bf16x8*)(Bs + (nf)      * 64 + kcB);
            bf16x8 b1 = *(const bf16x8*)(Bs + (nf + 32) * 64 + kcB);
            acc[0][0] = __builtin_amdgcn_mfma_f32_32x32x16_bf16(a0, b0, acc[0][0], 0, 0, 0);
            acc[0][1] = __builtin_amdgcn_mfma_f32_32x32x16_bf16(a0, b1, acc[0][1], 0, 0, 0);
            acc[1][0] = __builtin_amdgcn_mfma_f32_32x32x16_bf16(a1, b0, acc[1][0], 0, 0, 0);
            acc[1][1] = __builtin_amdgcn_mfma_f32_32x32x16_bf16(a1, b1, acc[1][1], 0, 0, 0);
        }
        __syncthreads();
    }

    // C/D: col = lane&31 (n), row = (reg&3) + 8*(reg>>2) + 4*half (+ 32*i_m)
    if (MODE == EPI_FIN) {
        float* O = (float*)Out + (size_t)bz * sO;
        const float* R = res + (size_t)bz * sR;
        #pragma unroll
        for (int im = 0; im < 2; ++im)
            #pragma unroll
            for (int g4 = 0; g4 < 4; ++g4) {
                const int mb = m0 + wm + im * 32 + g4 * 8 + half * 4;
                #pragma unroll
                for (int jn = 0; jn < 2; ++jn) {
                    const int n = n0 + wn + jn * 32 + col;
                    const float bb = bias[n];
                    const size_t base = (size_t)n * ldo + mb;
                    const f32x4v r4 = __builtin_nontemporal_load((const f32x4v*)&R[base]);
                    f32x4v o4;
                    o4.x = acc[im][jn][g4 * 4 + 0] + bb + r4.x;
                    o4.y = acc[im][jn][g4 * 4 + 1] + bb + r4.y;
                    o4.z = acc[im][jn][g4 * 4 + 2] + bb + r4.z;
                    o4.w = acc[im][jn][g4 * 4 + 3] + bb + r4.w;
                    __builtin_nontemporal_store(o4, (f32x4v*)&O[base]);
                }
            }
    } else if (MODE == EPI_EXP) {
        u16* O = (u16*)Out + (size_t)bz * sO;
        float* RS = rsum + (size_t)bz * sRS;
        float psum[2] = {0.f, 0.f};
        #pragma unroll
        for (int im = 0; im < 2; ++im)
            #pragma unroll
            for (int g4 = 0; g4 < 4; ++g4) {
                const int mb = m0 + wm + im * 32 + g4 * 8 + half * 4;
                #pragma unroll
                for (int jn = 0; jn < 2; ++jn) {
                    const int n = n0 + wn + jn * 32 + col;
                    u16 h0 = f2bf(__expf(acc[im][jn][g4 * 4 + 0] * alpha));
                    u16 h1 = f2bf(__expf(acc[im][jn][g4 * 4 + 1] * alpha));
                    u16 h2 = f2bf(__expf(acc[im][jn][g4 * 4 + 2] * alpha));
                    u16 h3 = f2bf(__expf(acc[im][jn][g4 * 4 + 3] * alpha));
                    psum[jn] += bf2f(h0) + bf2f(h1) + bf2f(h2) + bf2f(h3);
                    nt_store_u4(make_ushort4(h0, h1, h2, h3), &O[(size_t)n * ldo + mb]);
                }
            }
        #pragma unroll
        for (int jn = 0; jn < 2; ++jn) psum[jn] += __shfl_xor(psum[jn], 32, 64);
        if (half == 0) {
            #pragma unroll
            for (int jn = 0; jn < 2; ++jn)
                atomicAdd(&RS[n0 + wn + jn * 32 + col], psum[jn]);
        }
    } else {
        u16* O;
        const float* bi = bias;
        const float* RS = (MODE == EPI_TNRM) ? rsum + (size_t)bz * sRS : nullptr;
        int mbase = m0 + wm;
        if (MODE == EPI_QK) {
            const bool hi = (m0 & 512) != 0;
            O  = (u16*)(hi ? Out2 : Out) + (size_t)bz * sO;
            bi = hi ? bias2 : bias;
            mbase = (m0 & 511) + wm;
        } else {
            O = (u16*)Out + (size_t)bz * sO;
        }
        float inv[2];
        if (MODE == EPI_TNRM) {
            inv[0] = 1.f / RS[n0 + wn + col];
            inv[1] = 1.f / RS[n0 + wn + 32 + col];
        }
        #pragma unroll
        for (int im = 0; im < 2; ++im)
            #pragma unroll
            for (int g4 = 0; g4 < 4; ++g4) {
                const int mb = mbase + im * 32 + g4 * 8 + half * 4;
                float4 bm = make_float4(0.f, 0.f, 0.f, 0.f);
                if (MODE == EPI_QK) bm = *(const float4*)&bi[mb];
                #pragma unroll
                for (int jn = 0; jn < 2; ++jn) {
                    const int n = n0 + wn + jn * 32 + col;
                    float v0 = acc[im][jn][g4 * 4 + 0];
                    float v1 = acc[im][jn][g4 * 4 + 1];
                    float v2 = acc[im][jn][g4 * 4 + 2];
                    float v3 = acc[im][jn][g4 * 4 + 3];
                    if (MODE == EPI_QK)  { v0 += bm.x; v1 += bm.y; v2 += bm.z; v3 += bm.w; }
                    if (MODE == EPI_TBN) { const float bb = bi[n]; v0 += bb; v1 += bb; v2 += bb; v3 += bb; }
                    if (MODE == EPI_TNRM) { v0 *= inv[jn]; v1 *= inv[jn]; v2 *= inv[jn]; v3 *= inv[jn]; }
                    ushort4 pk = make_ushort4(f2bf(v0), f2bf(v1), f2bf(v2), f2bf(v3));
                    *(ushort4*)&O[(size_t)n * ldo + mb] = pk;
                }
            }
    }
}

// ---------------------------------------------------------------------------
extern "C" void kernel_launch(void* const* d_in, const int* in_sizes, int n_in,
                              void* d_out, int out_size, void* d_ws, size_t ws_size,
                              hipStream_t stream) {
    const float* x    = (const float*)d_in[0];
    const float* gn_w = (const float*)d_in[1];
    const float* gn_b = (const float*)d_in[2];
    const float* wq   = (const float*)d_in[3];
    const float* bq   = (const float*)d_in[4];
    const float* wk   = (const float*)d_in[5];
    const float* bk   = (const float*)d_in[6];
    const float* wv   = (const float*)d_in[7];
    const float* bv   = (const float*)d_in[8];
    const float* wo   = (const float*)d_in[9];
    const float* bo   = (const float*)d_in[10];
    float* out = (float*)d_out;

    char* p = (char*)d_ws;
    const size_t WSZ = (size_t)CH * CH * 2;
    const size_t HSZ = (size_t)BATCH * CH * LEN * 2;
    u16* Wqk = (u16*)p; p += 2 * WSZ;   // rows 0-511 = Wq, 512-1023 = Wk
    u16* Wvb = (u16*)p; p += WSZ;
    u16* Wob = (u16*)p; p += WSZ;
    u16* Ht  = (u16*)p; p += HSZ;   // GN out [b][l][c]; later PV out [b][i][c]
    u16* Qt  = (u16*)p; p += HSZ;   // [b][l][c]
    u16* Kt  = (u16*)p; p += HSZ;   // [b][l][c]
    u16* Vb  = (u16*)p; p += HSZ;   // [b][c][l]
    u16* Sb  = (u16*)p; p += (size_t)BATCH * LEN * LEN * 2;  // exp(scores)
    float* gnA = (float*)p; p += (size_t)BATCH * CH * 4;
    float* gnB = (float*)p; p += (size_t)BATCH * CH * 4;
    float* rowsum = (float*)p;      // BATCH * LEN fp32

    const long long sH = (long long)LEN * CH;
    const long long sV = (long long)CH * LEN;
    const long long sS = (long long)LEN * LEN;
    const float scale = 0.04419417382415922f;   // 512^-0.5

    wconv4<<<dim3(256, 4), 256, 0, stream>>>(wq, wk, wv, wo,
                                             Wqk, Wqk + (size_t)CH * CH, Wvb, Wob);
    gn_stats<<<BATCH * NG, 256, 0, stream>>>(x, gn_w, gn_b, gnA, gnB);
    gn_apply_t<<<dim3(LEN / 64, CH / 64, BATCH), 256, 0, stream>>>(x, gnA, gnB, Ht);
    zerof4<<<BATCH * LEN / 1024, 256, 0, stream>>>((float4*)rowsum);

    // Q+K fused: A=Wqk (m=o), B=Ht (n=l) -> Qt/Kt[l][o] packed in o
    gemm_bt<EPI_QK><<<dim3(16, 8, 8), 256, 0, stream>>>(
        Wqk, CH, 0, Ht, CH, sH, Qt, Kt, CH, sH, bq, bk, nullptr, 0, nullptr, 0, CH, 0.f);
    // V: A=Ht (m=l), B=Wv (n=c) -> Vb[c][l] packed in l, bias[c]
    gemm_bt<EPI_TBN><<<dim3(4, 16, 8), 256, 0, stream>>>(
        Ht, CH, sH, Wvb, CH, 0, Vb, nullptr, LEN, sV, bv, nullptr, nullptr, 0, nullptr, 0, CH, 0.f);
    // scores: A=Kt (m=j), B=Qt (n=i) -> E[i][j]=exp(scale*S) packed in j, rowsum[i]
    gemm_bt<EPI_EXP><<<dim3(16, 16, 8), 256, 0, stream>>>(
        Kt, CH, sH, Qt, CH, sH, Sb, nullptr, LEN, sS, nullptr, nullptr, nullptr, 0, rowsum, LEN, CH, scale);
    // PV: A=Vb (m=c), B=E (n=i) -> Ht[i][c] packed in c, * 1/rowsum[i]
    gemm_bt<EPI_TNRM><<<dim3(16, 4, 8), 256, 0, stream>>>(
        Vb, LEN, sV, Sb, LEN, sS, Ht, nullptr, CH, sH, nullptr, nullptr, nullptr, 0, rowsum, LEN, LEN, 0.f);
    // final: A=Ht (m=l), B=Wo (n=o) -> out[o][l] f32 + bias[o] + x residual
    gemm_bt<EPI_FIN><<<dim3(4, 16, 8), 256, 0, stream>>>(
        Ht, CH, sH, Wob, CH, 0, out, nullptr, LEN, sV, bo, nullptr, x, sV, nullptr, 0, CH, 0.f);
}

// Round 8
// 292.864 us; speedup vs baseline: 1.6086x; 1.6086x over previous
//
#include <hip/hip_runtime.h>
#include <math.h>

#define BATCH 8
#define CH 512
#define LEN 2048
#define NG 32
#define CPG 16

typedef unsigned short u16;
typedef __bf16 bf16x8 __attribute__((ext_vector_type(8)));
typedef float f32x16 __attribute__((ext_vector_type(16)));

__device__ __forceinline__ u16 f2bf(float f) {
    union { float f; unsigned u; } c; c.f = f;
    unsigned r = c.u + 0x7fffu + ((c.u >> 16) & 1u);   // RNE
    return (u16)(r >> 16);
}
__device__ __forceinline__ float bf2f(u16 h) {
    union { unsigned u; float f; } c; c.u = ((unsigned)h) << 16;
    return c.f;
}
__device__ __forceinline__ void gload16(const u16* g, u16* l) {
    __builtin_amdgcn_global_load_lds(
        (const __attribute__((address_space(1))) unsigned int*)g,
        (__attribute__((address_space(3))) unsigned int*)l, 16, 0, 0);
}

// ---------------------------------------------------------------------------
__global__ __launch_bounds__(256) void zerof4(float4* __restrict__ p) {
    p[blockIdx.x * 256 + threadIdx.x] = make_float4(0.f, 0.f, 0.f, 0.f);
}

// ---------------------------------------------------------------------------
__global__ __launch_bounds__(256) void wconv4(const float* __restrict__ w0, const float* __restrict__ w1,
                                              const float* __restrict__ w2, const float* __restrict__ w3,
                                              u16* __restrict__ o0, u16* __restrict__ o1,
                                              u16* __restrict__ o2, u16* __restrict__ o3) {
    const float* s; u16* d;
    switch (blockIdx.y) {
        case 0: s = w0; d = o0; break;
        case 1: s = w1; d = o1; break;
        case 2: s = w2; d = o2; break;
        default: s = w3; d = o3; break;
    }
    const int i = blockIdx.x * 256 + threadIdx.x;
    float4 f = ((const float4*)s)[i];
    ushort4 o = make_ushort4(f2bf(f.x), f2bf(f.y), f2bf(f.z), f2bf(f.w));
    ((ushort4*)d)[i] = o;
}

// ---------------------------------------------------------------------------
__global__ __launch_bounds__(256) void gn_stats(const float* __restrict__ x,
                                                const float* __restrict__ gw,
                                                const float* __restrict__ gb,
                                                float* __restrict__ gnA,
                                                float* __restrict__ gnB) {
    const int b = blockIdx.x >> 5, g = blockIdx.x & 31;
    const float4* xp = (const float4*)(x + ((size_t)b * CH + (size_t)g * CPG) * LEN);
    float s = 0.f, s2 = 0.f;
    for (int i = threadIdx.x; i < (CPG * LEN) / 4; i += 256) {
        float4 v = xp[i];
        s += v.x + v.y + v.z + v.w;
        s2 = fmaf(v.x, v.x, fmaf(v.y, v.y, fmaf(v.z, v.z, fmaf(v.w, v.w, s2))));
    }
    #pragma unroll
    for (int off = 32; off > 0; off >>= 1) {
        s  += __shfl_down(s, off, 64);
        s2 += __shfl_down(s2, off, 64);
    }
    __shared__ float sm[2][4];
    const int lane = threadIdx.x & 63, wv = threadIdx.x >> 6;
    if (lane == 0) { sm[0][wv] = s; sm[1][wv] = s2; }
    __syncthreads();
    if (threadIdx.x < CPG) {
        const float S  = sm[0][0] + sm[0][1] + sm[0][2] + sm[0][3];
        const float S2 = sm[1][0] + sm[1][1] + sm[1][2] + sm[1][3];
        const float mean = S * (1.f / (CPG * LEN));
        const float var  = S2 * (1.f / (CPG * LEN)) - mean * mean;
        const float rstd = rsqrtf(var + 1e-6f);
        const int c = g * CPG + threadIdx.x;
        const float sc = rstd * gw[c];
        gnA[b * CH + c] = sc;
        gnB[b * CH + c] = gb[c] - mean * sc;
    }
}

// ---------------------------------------------------------------------------
__global__ __launch_bounds__(256) void gn_apply_t(const float* __restrict__ x,
                                                  const float* __restrict__ gnA,
                                                  const float* __restrict__ gnB,
                                                  u16* __restrict__ Ht) {
    __shared__ float tile[64][65];
    const int b = blockIdx.z, c0 = blockIdx.y * 64, l0 = blockIdx.x * 64;
    const int t = threadIdx.x, tl = t & 63, tr = t >> 6;
    #pragma unroll 4
    for (int i = 0; i < 16; ++i) {
        const int c = tr + i * 4;
        const float a = gnA[b * CH + c0 + c];
        const float sh = gnB[b * CH + c0 + c];
        tile[c][tl] = x[((size_t)b * CH + c0 + c) * LEN + l0 + tl] * a + sh;
    }
    __syncthreads();
    #pragma unroll 4
    for (int i = 0; i < 16; ++i) {
        const int l = tr + i * 4;
        Ht[((size_t)b * LEN + l0 + l) * CH + c0 + tl] = f2bf(tile[tl][l]);
    }
}

// ---------------------------------------------------------------------------
// MFMA GEMM (B^T form), 128x128 tile, BK=64, mfma_f32_32x32x16_bf16.
// r4 schedule (proven best: single-buffer, 2-barrier, 256 thr / 4 waves,
// 4 blocks/CU via __launch_bounds__(256,4)) + round-8 memory-system fixes
// (the two r7 changes the counters endorsed; nt-stores REVERTED — they
// write-through partial 64B lines on these column-scattered epilogues,
// 3.2x HBM write amplification, r7 regression):
//  (1) bijective XCD remap: each XCD gets a contiguous chunk of flat tile
//      space (whole batches here), so its 4MB L2 holds ONE batch's panels
//      (r7 measured: scores FETCH 74 -> 16.8 MB).
//  (2) PV (EPI_TNRM) uses m(c)-fast in-XCD order: 4 consecutive blocks share
//      one Sb i-panel (512KB) with all of Vb (2MB) L2-resident -> Sb fetched
//      ~once instead of ~4x.
// LDS k-chunks XOR-swizzled by row (chunk stored at c = kc ^ (row&7)) via the
// GLOBAL source address (global_load_lds dest must stay lane-contiguous).
// ---------------------------------------------------------------------------
#define EPI_QK   0   // bf16; (Out,bias)/(Out2,bias2) by m half; +bias[m]
#define EPI_TBN  1   // bf16; +bias[n]
#define EPI_EXP  2   // bf16; exp(acc*alpha), accumulate rowsum[n]
#define EPI_TNRM 3   // bf16; * (1/rowsum[n]); m-fast block order
#define EPI_FIN  4   // f32;  +bias[n] + res

template <int MODE>
__global__ __launch_bounds__(256, 4) void gemm_bt(
    const u16* __restrict__ A, int lda, long long sA,
    const u16* __restrict__ B, int ldb, long long sB,
    void* __restrict__ Out, void* __restrict__ Out2,
    int ldo, long long sO,
    const float* __restrict__ bias, const float* __restrict__ bias2,
    const float* __restrict__ res, long long sR,
    float* __restrict__ rsum, long long sRS,
    int K, float alpha) {
    __shared__ u16 As[128 * 64];   // 16 KB
    __shared__ u16 Bs[128 * 64];   // 16 KB

    // ---- bijective XCD remap (all grids have nbk % 8 == 0)
    const int gx = gridDim.x, gy = gridDim.y;
    int flat = (blockIdx.z * gy + blockIdx.y) * gx + blockIdx.x;
    const int nbk = gx * gy * (int)gridDim.z;
    flat = (flat & 7) * (nbk >> 3) + (flat >> 3);
    const int bz = flat / (gx * gy);
    const int rr = flat - bz * gx * gy;
    int by, bx;
    if (MODE == EPI_TNRM) {   // m(c)-fast: share Sb i-panels, Vb L2-resident
        by = rr % gy; bx = rr / gy;
    } else {                  // n-fast: A-panel fixed, B batch L2-resident
        by = rr / gx; bx = rr % gx;
    }

    const int n0 = bx * 128, m0 = by * 128;
    A += (size_t)bz * sA;
    B += (size_t)bz * sB;
    const int t = threadIdx.x;
    const int lane = t & 63, wid = t >> 6;

    // staging: thread t owns LDS slots (row = t>>3 + g*32, chunk = t&7);
    // source chunk is XOR-swizzled: global chunk = (t&7) ^ (row&7)
    const int rowL = t >> 3, kq = (t & 7) ^ (rowL & 7);
    unsigned aoff = (unsigned)((m0 + rowL) * lda + kq * 8);
    unsigned boff = (unsigned)((n0 + rowL) * ldb + kq * 8);
    u16* const lds_dst_a = As + t * 8;
    u16* const lds_dst_b = Bs + t * 8;

    f32x16 acc[2][2];
    #pragma unroll
    for (int i = 0; i < 2; ++i)
        #pragma unroll
        for (int j = 0; j < 2; ++j)
            acc[i][j] = (f32x16)(0.f);

    const int col = lane & 31, half = lane >> 5;
    const int wm = (wid & 1) * 64, wn = (wid >> 1) * 64;
    const int mf = wm + col, nf = wn + col;
    const int mswz = mf & 7, nswz = nf & 7;   // row-invariant mod 8 for +32 rows

    for (int k0 = 0; k0 < K; k0 += 64) {
        #pragma unroll
        for (int g = 0; g < 4; ++g) {
            gload16(A + aoff + g * (32 * lda), lds_dst_a + g * 2048);
            gload16(B + boff + g * (32 * ldb), lds_dst_b + g * 2048);
        }
        aoff += 64; boff += 64;
        __syncthreads();
        #pragma unroll
        for (int ks = 0; ks < 4; ++ks) {
            const int kcA = ((ks * 2 + half) ^ mswz) * 8;
            const int kcB = ((ks * 2 + half) ^ nswz) * 8;
            bf16x8 a0 = *(const bf16x8*)(As + (mf)      * 64 + kcA);
            bf16x8 a1 = *(const bf16x8*)(As + (mf + 32) * 64 + kcA);
            bf16x8 b0 = *(const bf16x8*)(Bs + (nf)      * 64 + kcB);
            bf16x8 b1 = *(const bf16x8*)(Bs + (nf + 32) * 64 + kcB);
            acc[0][0] = __builtin_amdgcn_mfma_f32_32x32x16_bf16(a0, b0, acc[0][0], 0, 0, 0);
            acc[0][1] = __builtin_amdgcn_mfma_f32_32x32x16_bf16(a0, b1, acc[0][1], 0, 0, 0);
            acc[1][0] = __builtin_amdgcn_mfma_f32_32x32x16_bf16(a1, b0, acc[1][0], 0, 0, 0);
            acc[1][1] = __builtin_amdgcn_mfma_f32_32x32x16_bf16(a1, b1, acc[1][1], 0, 0, 0);
        }
        __syncthreads();
    }

    // C/D: col = lane&31 (n), row = (reg&3) + 8*(reg>>2) + 4*half (+ 32*i_m)
    if (MODE == EPI_FIN) {
        float* O = (float*)Out + (size_t)bz * sO;
        const float* R = res + (size_t)bz * sR;
        #pragma unroll
        for (int im = 0; im < 2; ++im)
            #pragma unroll
            for (int g4 = 0; g4 < 4; ++g4) {
                const int mb = m0 + wm + im * 32 + g4 * 8 + half * 4;
                #pragma unroll
                for (int jn = 0; jn < 2; ++jn) {
                    const int n = n0 + wn + jn * 32 + col;
                    const float bb = bias[n];
                    const size_t base = (size_t)n * ldo + mb;
                    const float4 r4 = *(const float4*)&R[base];
                    float4 o4;
                    o4.x = acc[im][jn][g4 * 4 + 0] + bb + r4.x;
                    o4.y = acc[im][jn][g4 * 4 + 1] + bb + r4.y;
                    o4.z = acc[im][jn][g4 * 4 + 2] + bb + r4.z;
                    o4.w = acc[im][jn][g4 * 4 + 3] + bb + r4.w;
                    *(float4*)&O[base] = o4;
                }
            }
    } else if (MODE == EPI_EXP) {
        u16* O = (u16*)Out + (size_t)bz * sO;
        float* RS = rsum + (size_t)bz * sRS;
        float psum[2] = {0.f, 0.f};
        #pragma unroll
        for (int im = 0; im < 2; ++im)
            #pragma unroll
            for (int g4 = 0; g4 < 4; ++g4) {
                const int mb = m0 + wm + im * 32 + g4 * 8 + half * 4;
                #pragma unroll
                for (int jn = 0; jn < 2; ++jn) {
                    const int n = n0 + wn + jn * 32 + col;
                    u16 h0 = f2bf(__expf(acc[im][jn][g4 * 4 + 0] * alpha));
                    u16 h1 = f2bf(__expf(acc[im][jn][g4 * 4 + 1] * alpha));
                    u16 h2 = f2bf(__expf(acc[im][jn][g4 * 4 + 2] * alpha));
                    u16 h3 = f2bf(__expf(acc[im][jn][g4 * 4 + 3] * alpha));
                    psum[jn] += bf2f(h0) + bf2f(h1) + bf2f(h2) + bf2f(h3);
                    *(ushort4*)&O[(size_t)n * ldo + mb] = make_ushort4(h0, h1, h2, h3);
                }
            }
        #pragma unroll
        for (int jn = 0; jn < 2; ++jn) psum[jn] += __shfl_xor(psum[jn], 32, 64);
        if (half == 0) {
            #pragma unroll
            for (int jn = 0; jn < 2; ++jn)
                atomicAdd(&RS[n0 + wn + jn * 32 + col], psum[jn]);
        }
    } else {
        u16* O;
        const float* bi = bias;
        const float* RS = (MODE == EPI_TNRM) ? rsum + (size_t)bz * sRS : nullptr;
        int mbase = m0 + wm;
        if (MODE == EPI_QK) {
            const bool hi = (m0 & 512) != 0;
            O  = (u16*)(hi ? Out2 : Out) + (size_t)bz * sO;
            bi = hi ? bias2 : bias;
            mbase = (m0 & 511) + wm;
        } else {
            O = (u16*)Out + (size_t)bz * sO;
        }
        float inv[2];
        if (MODE == EPI_TNRM) {
            inv[0] = 1.f / RS[n0 + wn + col];
            inv[1] = 1.f / RS[n0 + wn + 32 + col];
        }
        #pragma unroll
        for (int im = 0; im < 2; ++im)
            #pragma unroll
            for (int g4 = 0; g4 < 4; ++g4) {
                const int mb = mbase + im * 32 + g4 * 8 + half * 4;
                float4 bm = make_float4(0.f, 0.f, 0.f, 0.f);
                if (MODE == EPI_QK) bm = *(const float4*)&bi[mb];
                #pragma unroll
                for (int jn = 0; jn < 2; ++jn) {
                    const int n = n0 + wn + jn * 32 + col;
                    float v0 = acc[im][jn][g4 * 4 + 0];
                    float v1 = acc[im][jn][g4 * 4 + 1];
                    float v2 = acc[im][jn][g4 * 4 + 2];
                    float v3 = acc[im][jn][g4 * 4 + 3];
                    if (MODE == EPI_QK)  { v0 += bm.x; v1 += bm.y; v2 += bm.z; v3 += bm.w; }
                    if (MODE == EPI_TBN) { const float bb = bi[n]; v0 += bb; v1 += bb; v2 += bb; v3 += bb; }
                    if (MODE == EPI_TNRM) { v0 *= inv[jn]; v1 *= inv[jn]; v2 *= inv[jn]; v3 *= inv[jn]; }
                    ushort4 pk = make_ushort4(f2bf(v0), f2bf(v1), f2bf(v2), f2bf(v3));
                    *(ushort4*)&O[(size_t)n * ldo + mb] = pk;
                }
            }
    }
}

// ---------------------------------------------------------------------------
extern "C" void kernel_launch(void* const* d_in, const int* in_sizes, int n_in,
                              void* d_out, int out_size, void* d_ws, size_t ws_size,
                              hipStream_t stream) {
    const float* x    = (const float*)d_in[0];
    const float* gn_w = (const float*)d_in[1];
    const float* gn_b = (const float*)d_in[2];
    const float* wq   = (const float*)d_in[3];
    const float* bq   = (const float*)d_in[4];
    const float* wk   = (const float*)d_in[5];
    const float* bk   = (const float*)d_in[6];
    const float* wv   = (const float*)d_in[7];
    const float* bv   = (const float*)d_in[8];
    const float* wo   = (const float*)d_in[9];
    const float* bo   = (const float*)d_in[10];
    float* out = (float*)d_out;

    char* p = (char*)d_ws;
    const size_t WSZ = (size_t)CH * CH * 2;
    const size_t HSZ = (size_t)BATCH * CH * LEN * 2;
    u16* Wqk = (u16*)p; p += 2 * WSZ;   // rows 0-511 = Wq, 512-1023 = Wk
    u16* Wvb = (u16*)p; p += WSZ;
    u16* Wob = (u16*)p; p += WSZ;
    u16* Ht  = (u16*)p; p += HSZ;   // GN out [b][l][c]; later PV out [b][i][c]
    u16* Qt  = (u16*)p; p += HSZ;   // [b][l][c]
    u16* Kt  = (u16*)p; p += HSZ;   // [b][l][c]
    u16* Vb  = (u16*)p; p += HSZ;   // [b][c][l]
    u16* Sb  = (u16*)p; p += (size_t)BATCH * LEN * LEN * 2;  // exp(scores)
    float* gnA = (float*)p; p += (size_t)BATCH * CH * 4;
    float* gnB = (float*)p; p += (size_t)BATCH * CH * 4;
    float* rowsum = (float*)p;      // BATCH * LEN fp32

    const long long sH = (long long)LEN * CH;
    const long long sV = (long long)CH * LEN;
    const long long sS = (long long)LEN * LEN;
    const float scale = 0.04419417382415922f;   // 512^-0.5

    wconv4<<<dim3(256, 4), 256, 0, stream>>>(wq, wk, wv, wo,
                                             Wqk, Wqk + (size_t)CH * CH, Wvb, Wob);
    gn_stats<<<BATCH * NG, 256, 0, stream>>>(x, gn_w, gn_b, gnA, gnB);
    gn_apply_t<<<dim3(LEN / 64, CH / 64, BATCH), 256, 0, stream>>>(x, gnA, gnB, Ht);
    zerof4<<<BATCH * LEN / 1024, 256, 0, stream>>>((float4*)rowsum);

    // Q+K fused: A=Wqk (m=o), B=Ht (n=l) -> Qt/Kt[l][o] packed in o
    gemm_bt<EPI_QK><<<dim3(16, 8, 8), 256, 0, stream>>>(
        Wqk, CH, 0, Ht, CH, sH, Qt, Kt, CH, sH, bq, bk, nullptr, 0, nullptr, 0, CH, 0.f);
    // V: A=Ht (m=l), B=Wv (n=c) -> Vb[c][l] packed in l, bias[c]
    gemm_bt<EPI_TBN><<<dim3(4, 16, 8), 256, 0, stream>>>(
        Ht, CH, sH, Wvb, CH, 0, Vb, nullptr, LEN, sV, bv, nullptr, nullptr, 0, nullptr, 0, CH, 0.f);
    // scores: A=Kt (m=j), B=Qt (n=i) -> E[i][j]=exp(scale*S) packed in j, rowsum[i]
    gemm_bt<EPI_EXP><<<dim3(16, 16, 8), 256, 0, stream>>>(
        Kt, CH, sH, Qt, CH, sH, Sb, nullptr, LEN, sS, nullptr, nullptr, nullptr, 0, rowsum, LEN, CH, scale);
    // PV: A=Vb (m=c), B=E (n=i) -> Ht[i][c] packed in c, * 1/rowsum[i]
    gemm_bt<EPI_TNRM><<<dim3(16, 4, 8), 256, 0, stream>>>(
        Vb, LEN, sV, Sb, LEN, sS, Ht, nullptr, CH, sH, nullptr, nullptr, nullptr, 0, rowsum, LEN, LEN, 0.f);
    // final: A=Ht (m=l), B=Wo (n=o) -> out[o][l] f32 + bias[o] + x residual
    gemm_bt<EPI_FIN><<<dim3(4, 16, 8), 256, 0, stream>>>(
        Ht, CH, sH, Wob, CH, 0, out, nullptr, LEN, sV, bo, nullptr, x, sV, nullptr, 0, CH, 0.f);
}

// Round 9
// 275.765 us; speedup vs baseline: 1.7084x; 1.0620x over previous
//
#include <hip/hip_runtime.h>
#include <math.h>

#define BATCH 8
#define CH 512
#define LEN 2048
#define NG 32
#define CPG 16

typedef unsigned short u16;
typedef __bf16 bf16x8 __attribute__((ext_vector_type(8)));
typedef float f32x16 __attribute__((ext_vector_type(16)));

__device__ __forceinline__ u16 f2bf(float f) {
    union { float f; unsigned u; } c; c.f = f;
    unsigned r = c.u + 0x7fffu + ((c.u >> 16) & 1u);   // RNE
    return (u16)(r >> 16);
}
__device__ __forceinline__ float bf2f(u16 h) {
    union { unsigned u; float f; } c; c.u = ((unsigned)h) << 16;
    return c.f;
}
__device__ __forceinline__ void gload16(const u16* g, u16* l) {
    __builtin_amdgcn_global_load_lds(
        (const __attribute__((address_space(1))) unsigned int*)g,
        (__attribute__((address_space(3))) unsigned int*)l, 16, 0, 0);
}

// ---------------------------------------------------------------------------
__global__ __launch_bounds__(256) void zerof4(float4* __restrict__ p) {
    p[blockIdx.x * 256 + threadIdx.x] = make_float4(0.f, 0.f, 0.f, 0.f);
}

// ---------------------------------------------------------------------------
__global__ __launch_bounds__(256) void wconv4(const float* __restrict__ w0, const float* __restrict__ w1,
                                              const float* __restrict__ w2, const float* __restrict__ w3,
                                              u16* __restrict__ o0, u16* __restrict__ o1,
                                              u16* __restrict__ o2, u16* __restrict__ o3) {
    const float* s; u16* d;
    switch (blockIdx.y) {
        case 0: s = w0; d = o0; break;
        case 1: s = w1; d = o1; break;
        case 2: s = w2; d = o2; break;
        default: s = w3; d = o3; break;
    }
    const int i = blockIdx.x * 256 + threadIdx.x;
    float4 f = ((const float4*)s)[i];
    ushort4 o = make_ushort4(f2bf(f.x), f2bf(f.y), f2bf(f.z), f2bf(f.w));
    ((ushort4*)d)[i] = o;
}

// ---------------------------------------------------------------------------
// GN stats pass 1: 4-way split per (batch,group) for 4x the streaming TLP
// (old single-pass: 256 blocks = 1 block/CU = 12.5% occupancy, latency-bound).
// grid = BATCH*NG*4; each block partial-reduces 8192 f32 (2048 float4) and
// atomicAdds S/S2 into stats[0..255] / stats[256..511] (zeroed by zerof4).
// ---------------------------------------------------------------------------
__global__ __launch_bounds__(256) void gn_stats_p(const float* __restrict__ x,
                                                  float* __restrict__ stats) {
    const int blk = blockIdx.x;
    const int b = blk >> 7, g = (blk >> 2) & 31, sl = blk & 3;
    const float4* xp = (const float4*)(x + ((size_t)b * CH + (size_t)g * CPG) * LEN) + sl * 2048;
    float s = 0.f, s2 = 0.f;
    #pragma unroll
    for (int i = 0; i < 8; ++i) {
        float4 v = xp[threadIdx.x + i * 256];
        s += v.x + v.y + v.z + v.w;
        s2 = fmaf(v.x, v.x, fmaf(v.y, v.y, fmaf(v.z, v.z, fmaf(v.w, v.w, s2))));
    }
    #pragma unroll
    for (int off = 32; off > 0; off >>= 1) {
        s  += __shfl_down(s, off, 64);
        s2 += __shfl_down(s2, off, 64);
    }
    __shared__ float sm[2][4];
    const int lane = threadIdx.x & 63, wv = threadIdx.x >> 6;
    if (lane == 0) { sm[0][wv] = s; sm[1][wv] = s2; }
    __syncthreads();
    if (threadIdx.x == 0) {
        atomicAdd(&stats[b * NG + g],       sm[0][0] + sm[0][1] + sm[0][2] + sm[0][3]);
        atomicAdd(&stats[256 + b * NG + g], sm[1][0] + sm[1][1] + sm[1][2] + sm[1][3]);
    }
}

// finalize: stats -> per-channel affine (gnA = rstd*gw, gnB = gb - mean*gnA)
__global__ __launch_bounds__(256) void gn_fin(const float* __restrict__ stats,
                                              const float* __restrict__ gw,
                                              const float* __restrict__ gb,
                                              float* __restrict__ gnA,
                                              float* __restrict__ gnB) {
    const int idx = blockIdx.x * 256 + threadIdx.x;   // [0, BATCH*CH)
    const int b = idx >> 9, c = idx & 511, g = c >> 4;
    const float S  = stats[b * NG + g];
    const float S2 = stats[256 + b * NG + g];
    const float mean = S * (1.f / (CPG * LEN));
    const float var  = S2 * (1.f / (CPG * LEN)) - mean * mean;
    const float a = rsqrtf(var + 1e-6f) * gw[c];
    gnA[idx] = a;
    gnB[idx] = gb[c] - mean * a;
}

// ---------------------------------------------------------------------------
__global__ __launch_bounds__(256) void gn_apply_t(const float* __restrict__ x,
                                                  const float* __restrict__ gnA,
                                                  const float* __restrict__ gnB,
                                                  u16* __restrict__ Ht) {
    __shared__ float tile[64][65];
    const int b = blockIdx.z, c0 = blockIdx.y * 64, l0 = blockIdx.x * 64;
    const int t = threadIdx.x, tl = t & 63, tr = t >> 6;
    #pragma unroll 4
    for (int i = 0; i < 16; ++i) {
        const int c = tr + i * 4;
        const float a = gnA[b * CH + c0 + c];
        const float sh = gnB[b * CH + c0 + c];
        tile[c][tl] = x[((size_t)b * CH + c0 + c) * LEN + l0 + tl] * a + sh;
    }
    __syncthreads();
    #pragma unroll 4
    for (int i = 0; i < 16; ++i) {
        const int l = tr + i * 4;
        Ht[((size_t)b * LEN + l0 + l) * CH + c0 + tl] = f2bf(tile[tl][l]);
    }
}

// ---------------------------------------------------------------------------
// MFMA GEMM (B^T form), 128x128 tile, BK=64, mfma_f32_32x32x16_bf16.
// r4 schedule (proven best: single-buffer, 2-barrier, 256 thr / 4 waves,
// 4 blocks/CU via __launch_bounds__(256,4)).
// REMAP: bijective XCD remap applied ONLY to the scores GEMM (EPI_EXP) —
// the single r8 change the counters endorsed (FETCH 74->27 MB, -2.4 us).
// r8's remap+m-fast on the other GEMMs cost +8 us net -> reverted to
// r4-exact block order there.
// LDS k-chunks XOR-swizzled by row (chunk stored at c = kc ^ (row&7)) via the
// GLOBAL source address (global_load_lds dest must stay lane-contiguous).
// ---------------------------------------------------------------------------
#define EPI_QK   0   // bf16; (Out,bias)/(Out2,bias2) by m half; +bias[m]
#define EPI_TBN  1   // bf16; +bias[n]
#define EPI_EXP  2   // bf16; exp(acc*alpha), accumulate rowsum[n]; XCD remap
#define EPI_TNRM 3   // bf16; * (1/rowsum[n])
#define EPI_FIN  4   // f32;  +bias[n] + res

template <int MODE>
__global__ __launch_bounds__(256, 4) void gemm_bt(
    const u16* __restrict__ A, int lda, long long sA,
    const u16* __restrict__ B, int ldb, long long sB,
    void* __restrict__ Out, void* __restrict__ Out2,
    int ldo, long long sO,
    const float* __restrict__ bias, const float* __restrict__ bias2,
    const float* __restrict__ res, long long sR,
    float* __restrict__ rsum, long long sRS,
    int K, float alpha) {
    __shared__ u16 As[128 * 64];   // 16 KB
    __shared__ u16 Bs[128 * 64];   // 16 KB

    int bz, by, bx;
    if (MODE == EPI_EXP) {
        // bijective XCD remap (grid 16x16x8, nbk%8==0): each XCD keeps one
        // batch's Qt/Kt panels resident in its 4MB L2.
        const int gx = gridDim.x, gy = gridDim.y;
        int flat = (blockIdx.z * gy + blockIdx.y) * gx + blockIdx.x;
        const int nbk = gx * gy * (int)gridDim.z;
        flat = (flat & 7) * (nbk >> 3) + (flat >> 3);
        bz = flat / (gx * gy);
        const int rr = flat - bz * gx * gy;
        by = rr / gx;
        bx = rr - by * gx;
    } else {
        bz = blockIdx.z; by = blockIdx.y; bx = blockIdx.x;
    }

    const int n0 = bx * 128, m0 = by * 128;
    A += (size_t)bz * sA;
    B += (size_t)bz * sB;
    const int t = threadIdx.x;
    const int lane = t & 63, wid = t >> 6;

    // staging: thread t owns LDS slots (row = t>>3 + g*32, chunk = t&7);
    // source chunk is XOR-swizzled: global chunk = (t&7) ^ (row&7)
    const int rowL = t >> 3, kq = (t & 7) ^ (rowL & 7);
    unsigned aoff = (unsigned)((m0 + rowL) * lda + kq * 8);
    unsigned boff = (unsigned)((n0 + rowL) * ldb + kq * 8);
    u16* const lds_dst_a = As + t * 8;
    u16* const lds_dst_b = Bs + t * 8;

    f32x16 acc[2][2];
    #pragma unroll
    for (int i = 0; i < 2; ++i)
        #pragma unroll
        for (int j = 0; j < 2; ++j)
            acc[i][j] = (f32x16)(0.f);

    const int col = lane & 31, half = lane >> 5;
    const int wm = (wid & 1) * 64, wn = (wid >> 1) * 64;
    const int mf = wm + col, nf = wn + col;
    const int mswz = mf & 7, nswz = nf & 7;   // row-invariant mod 8 for +32 rows

    for (int k0 = 0; k0 < K; k0 += 64) {
        #pragma unroll
        for (int g = 0; g < 4; ++g) {
            gload16(A + aoff + g * (32 * lda), lds_dst_a + g * 2048);
            gload16(B + boff + g * (32 * ldb), lds_dst_b + g * 2048);
        }
        aoff += 64; boff += 64;
        __syncthreads();
        #pragma unroll
        for (int ks = 0; ks < 4; ++ks) {
            const int kcA = ((ks * 2 + half) ^ mswz) * 8;
            const int kcB = ((ks * 2 + half) ^ nswz) * 8;
            bf16x8 a0 = *(const bf16x8*)(As + (mf)      * 64 + kcA);
            bf16x8 a1 = *(const bf16x8*)(As + (mf + 32) * 64 + kcA);
            bf16x8 b0 = *(const bf16x8*)(Bs + (nf)      * 64 + kcB);
            bf16x8 b1 = *(const bf16x8*)(Bs + (nf + 32) * 64 + kcB);
            acc[0][0] = __builtin_amdgcn_mfma_f32_32x32x16_bf16(a0, b0, acc[0][0], 0, 0, 0);
            acc[0][1] = __builtin_amdgcn_mfma_f32_32x32x16_bf16(a0, b1, acc[0][1], 0, 0, 0);
            acc[1][0] = __builtin_amdgcn_mfma_f32_32x32x16_bf16(a1, b0, acc[1][0], 0, 0, 0);
            acc[1][1] = __builtin_amdgcn_mfma_f32_32x32x16_bf16(a1, b1, acc[1][1], 0, 0, 0);
        }
        __syncthreads();
    }

    // C/D: col = lane&31 (n), row = (reg&3) + 8*(reg>>2) + 4*half (+ 32*i_m)
    if (MODE == EPI_FIN) {
        float* O = (float*)Out + (size_t)bz * sO;
        const float* R = res + (size_t)bz * sR;
        #pragma unroll
        for (int im = 0; im < 2; ++im)
            #pragma unroll
            for (int g4 = 0; g4 < 4; ++g4) {
                const int mb = m0 + wm + im * 32 + g4 * 8 + half * 4;
                #pragma unroll
                for (int jn = 0; jn < 2; ++jn) {
                    const int n = n0 + wn + jn * 32 + col;
                    const float bb = bias[n];
                    const size_t base = (size_t)n * ldo + mb;
                    const float4 r4 = *(const float4*)&R[base];
                    float4 o4;
                    o4.x = acc[im][jn][g4 * 4 + 0] + bb + r4.x;
                    o4.y = acc[im][jn][g4 * 4 + 1] + bb + r4.y;
                    o4.z = acc[im][jn][g4 * 4 + 2] + bb + r4.z;
                    o4.w = acc[im][jn][g4 * 4 + 3] + bb + r4.w;
                    *(float4*)&O[base] = o4;
                }
            }
    } else if (MODE == EPI_EXP) {
        u16* O = (u16*)Out + (size_t)bz * sO;
        float* RS = rsum + (size_t)bz * sRS;
        float psum[2] = {0.f, 0.f};
        #pragma unroll
        for (int im = 0; im < 2; ++im)
            #pragma unroll
            for (int g4 = 0; g4 < 4; ++g4) {
                const int mb = m0 + wm + im * 32 + g4 * 8 + half * 4;
                #pragma unroll
                for (int jn = 0; jn < 2; ++jn) {
                    const int n = n0 + wn + jn * 32 + col;
                    u16 h0 = f2bf(__expf(acc[im][jn][g4 * 4 + 0] * alpha));
                    u16 h1 = f2bf(__expf(acc[im][jn][g4 * 4 + 1] * alpha));
                    u16 h2 = f2bf(__expf(acc[im][jn][g4 * 4 + 2] * alpha));
                    u16 h3 = f2bf(__expf(acc[im][jn][g4 * 4 + 3] * alpha));
                    psum[jn] += bf2f(h0) + bf2f(h1) + bf2f(h2) + bf2f(h3);
                    *(ushort4*)&O[(size_t)n * ldo + mb] = make_ushort4(h0, h1, h2, h3);
                }
            }
        #pragma unroll
        for (int jn = 0; jn < 2; ++jn) psum[jn] += __shfl_xor(psum[jn], 32, 64);
        if (half == 0) {
            #pragma unroll
            for (int jn = 0; jn < 2; ++jn)
                atomicAdd(&RS[n0 + wn + jn * 32 + col], psum[jn]);
        }
    } else {
        u16* O;
        const float* bi = bias;
        const float* RS = (MODE == EPI_TNRM) ? rsum + (size_t)bz * sRS : nullptr;
        int mbase = m0 + wm;
        if (MODE == EPI_QK) {
            const bool hi = (m0 & 512) != 0;
            O  = (u16*)(hi ? Out2 : Out) + (size_t)bz * sO;
            bi = hi ? bias2 : bias;
            mbase = (m0 & 511) + wm;
        } else {
            O = (u16*)Out + (size_t)bz * sO;
        }
        float inv[2];
        if (MODE == EPI_TNRM) {
            inv[0] = 1.f / RS[n0 + wn + col];
            inv[1] = 1.f / RS[n0 + wn + 32 + col];
        }
        #pragma unroll
        for (int im = 0; im < 2; ++im)
            #pragma unroll
            for (int g4 = 0; g4 < 4; ++g4) {
                const int mb = mbase + im * 32 + g4 * 8 + half * 4;
                float4 bm = make_float4(0.f, 0.f, 0.f, 0.f);
                if (MODE == EPI_QK) bm = *(const float4*)&bi[mb];
                #pragma unroll
                for (int jn = 0; jn < 2; ++jn) {
                    const int n = n0 + wn + jn * 32 + col;
                    float v0 = acc[im][jn][g4 * 4 + 0];
                    float v1 = acc[im][jn][g4 * 4 + 1];
                    float v2 = acc[im][jn][g4 * 4 + 2];
                    float v3 = acc[im][jn][g4 * 4 + 3];
                    if (MODE == EPI_QK)  { v0 += bm.x; v1 += bm.y; v2 += bm.z; v3 += bm.w; }
                    if (MODE == EPI_TBN) { const float bb = bi[n]; v0 += bb; v1 += bb; v2 += bb; v3 += bb; }
                    if (MODE == EPI_TNRM) { v0 *= inv[jn]; v1 *= inv[jn]; v2 *= inv[jn]; v3 *= inv[jn]; }
                    ushort4 pk = make_ushort4(f2bf(v0), f2bf(v1), f2bf(v2), f2bf(v3));
                    *(ushort4*)&O[(size_t)n * ldo + mb] = pk;
                }
            }
    }
}

// ---------------------------------------------------------------------------
extern "C" void kernel_launch(void* const* d_in, const int* in_sizes, int n_in,
                              void* d_out, int out_size, void* d_ws, size_t ws_size,
                              hipStream_t stream) {
    const float* x    = (const float*)d_in[0];
    const float* gn_w = (const float*)d_in[1];
    const float* gn_b = (const float*)d_in[2];
    const float* wq   = (const float*)d_in[3];
    const float* bq   = (const float*)d_in[4];
    const float* wk   = (const float*)d_in[5];
    const float* bk   = (const float*)d_in[6];
    const float* wv   = (const float*)d_in[7];
    const float* bv   = (const float*)d_in[8];
    const float* wo   = (const float*)d_in[9];
    const float* bo   = (const float*)d_in[10];
    float* out = (float*)d_out;

    char* p = (char*)d_ws;
    const size_t WSZ = (size_t)CH * CH * 2;
    const size_t HSZ = (size_t)BATCH * CH * LEN * 2;
    u16* Wqk = (u16*)p; p += 2 * WSZ;   // rows 0-511 = Wq, 512-1023 = Wk
    u16* Wvb = (u16*)p; p += WSZ;
    u16* Wob = (u16*)p; p += WSZ;
    u16* Ht  = (u16*)p; p += HSZ;   // GN out [b][l][c]; later PV out [b][i][c]
    u16* Qt  = (u16*)p; p += HSZ;   // [b][l][c]
    u16* Kt  = (u16*)p; p += HSZ;   // [b][l][c]
    u16* Vb  = (u16*)p; p += HSZ;   // [b][c][l]
    u16* Sb  = (u16*)p; p += (size_t)BATCH * LEN * LEN * 2;  // exp(scores)
    float* gnA = (float*)p; p += (size_t)BATCH * CH * 4;
    float* gnB = (float*)p; p += (size_t)BATCH * CH * 4;
    float* rowsum = (float*)p; p += (size_t)BATCH * LEN * 4; // 16384 f32
    float* stats  = (float*)p;      // 512 f32 (S | S2), zeroed with rowsum

    const long long sH = (long long)LEN * CH;
    const long long sV = (long long)CH * LEN;
    const long long sS = (long long)LEN * LEN;
    const float scale = 0.04419417382415922f;   // 512^-0.5

    // zero rowsum (16384 f32) + stats (512 f32) = 16896 f32 -> 17 blocks
    // of 256 float4 cover 17408 f32 (allocation above leaves headroom).
    zerof4<<<17, 256, 0, stream>>>((float4*)rowsum);
    wconv4<<<dim3(256, 4), 256, 0, stream>>>(wq, wk, wv, wo,
                                             Wqk, Wqk + (size_t)CH * CH, Wvb, Wob);
    gn_stats_p<<<BATCH * NG * 4, 256, 0, stream>>>(x, stats);
    gn_fin<<<BATCH * CH / 256, 256, 0, stream>>>(stats, gn_w, gn_b, gnA, gnB);
    gn_apply_t<<<dim3(LEN / 64, CH / 64, BATCH), 256, 0, stream>>>(x, gnA, gnB, Ht);

    // Q+K fused: A=Wqk (m=o), B=Ht (n=l) -> Qt/Kt[l][o] packed in o
    gemm_bt<EPI_QK><<<dim3(16, 8, 8), 256, 0, stream>>>(
        Wqk, CH, 0, Ht, CH, sH, Qt, Kt, CH, sH, bq, bk, nullptr, 0, nullptr, 0, CH, 0.f);
    // V: A=Ht (m=l), B=Wv (n=c) -> Vb[c][l] packed in l, bias[c]
    gemm_bt<EPI_TBN><<<dim3(4, 16, 8), 256, 0, stream>>>(
        Ht, CH, sH, Wvb, CH, 0, Vb, nullptr, LEN, sV, bv, nullptr, nullptr, 0, nullptr, 0, CH, 0.f);
    // scores: A=Kt (m=j), B=Qt (n=i) -> E[i][j]=exp(scale*S) packed in j, rowsum[i]
    gemm_bt<EPI_EXP><<<dim3(16, 16, 8), 256, 0, stream>>>(
        Kt, CH, sH, Qt, CH, sH, Sb, nullptr, LEN, sS, nullptr, nullptr, nullptr, 0, rowsum, LEN, CH, scale);
    // PV: A=Vb (m=c), B=E (n=i) -> Ht[i][c] packed in c, * 1/rowsum[i]
    gemm_bt<EPI_TNRM><<<dim3(16, 4, 8), 256, 0, stream>>>(
        Vb, LEN, sV, Sb, LEN, sS, Ht, nullptr, CH, sH, nullptr, nullptr, nullptr, 0, rowsum, LEN, LEN, 0.f);
    // final: A=Ht (m=l), B=Wo (n=o) -> out[o][l] f32 + bias[o] + x residual
    gemm_bt<EPI_FIN><<<dim3(4, 16, 8), 256, 0, stream>>>(
        Ht, CH, sH, Wob, CH, 0, out, nullptr, LEN, sV, bo, nullptr, x, sV, nullptr, 0, CH, 0.f);
}

// Round 10
// 271.398 us; speedup vs baseline: 1.7359x; 1.0161x over previous
//
#include <hip/hip_runtime.h>
#include <math.h>

#define BATCH 8
#define CH 512
#define LEN 2048
#define NG 32
#define CPG 16

typedef unsigned short u16;
typedef __bf16 bf16x8 __attribute__((ext_vector_type(8)));
typedef float f32x16 __attribute__((ext_vector_type(16)));

__device__ __forceinline__ u16 f2bf(float f) {
    union { float f; unsigned u; } c; c.f = f;
    unsigned r = c.u + 0x7fffu + ((c.u >> 16) & 1u);   // RNE
    return (u16)(r >> 16);
}
__device__ __forceinline__ float bf2f(u16 h) {
    union { unsigned u; float f; } c; c.u = ((unsigned)h) << 16;
    return c.f;
}
__device__ __forceinline__ void gload16(const u16* g, u16* l) {
    __builtin_amdgcn_global_load_lds(
        (const __attribute__((address_space(1))) unsigned int*)g,
        (__attribute__((address_space(3))) unsigned int*)l, 16, 0, 0);
}

// ---------------------------------------------------------------------------
// fused pre-pass, one launch, 3 independent block ranges:
//  [0,16)       zero rowsum (16 x 256 x float4 = 16384 f32)
//  [16,1040)    weight f32->bf16 conversion (4 x 256 blocks)
//  [1040,2064)  GN stats partials: 4 slots per (b,g), PLAIN stores (no
//               atomics -> no zero-init dependency, race-free in one launch)
// ---------------------------------------------------------------------------
__global__ __launch_bounds__(256) void fused_pre(
    const float* __restrict__ x,
    const float* __restrict__ w0, const float* __restrict__ w1,
    const float* __restrict__ w2, const float* __restrict__ w3,
    u16* __restrict__ o0, u16* __restrict__ o1,
    u16* __restrict__ o2, u16* __restrict__ o3,
    float4* __restrict__ zbuf, float* __restrict__ stats) {
    const int blk = blockIdx.x;
    if (blk < 16) {
        zbuf[blk * 256 + threadIdx.x] = make_float4(0.f, 0.f, 0.f, 0.f);
    } else if (blk < 1040) {
        const int wb = blk - 16;
        const float* s; u16* d;
        switch (wb >> 8) {
            case 0: s = w0; d = o0; break;
            case 1: s = w1; d = o1; break;
            case 2: s = w2; d = o2; break;
            default: s = w3; d = o3; break;
        }
        const int i = (wb & 255) * 256 + threadIdx.x;
        float4 f = ((const float4*)s)[i];
        ((ushort4*)d)[i] = make_ushort4(f2bf(f.x), f2bf(f.y), f2bf(f.z), f2bf(f.w));
    } else {
        const int sb = blk - 1040;
        const int b = sb >> 7, g = (sb >> 2) & 31, sl = sb & 3;
        const float4* xp = (const float4*)(x + ((size_t)b * CH + (size_t)g * CPG) * LEN) + sl * 2048;
        float s = 0.f, s2 = 0.f;
        #pragma unroll
        for (int i = 0; i < 8; ++i) {
            float4 v = xp[threadIdx.x + i * 256];
            s += v.x + v.y + v.z + v.w;
            s2 = fmaf(v.x, v.x, fmaf(v.y, v.y, fmaf(v.z, v.z, fmaf(v.w, v.w, s2))));
        }
        #pragma unroll
        for (int off = 32; off > 0; off >>= 1) {
            s  += __shfl_down(s, off, 64);
            s2 += __shfl_down(s2, off, 64);
        }
        __shared__ float sm[2][4];
        const int lane = threadIdx.x & 63, wv = threadIdx.x >> 6;
        if (lane == 0) { sm[0][wv] = s; sm[1][wv] = s2; }
        __syncthreads();
        if (threadIdx.x == 0) {
            const int base = (b * NG + g) * 4 + sl;
            stats[base]        = sm[0][0] + sm[0][1] + sm[0][2] + sm[0][3];
            stats[1024 + base] = sm[1][0] + sm[1][1] + sm[1][2] + sm[1][3];
        }
    }
}

// ---------------------------------------------------------------------------
// GN apply + [c][l]->[l][c] transpose. Round-10: affine computed in-block
// from the 4 stats partials (gn_fin kernel eliminated); float4 x reads
// (16B/lane) and ushort4 Ht writes (8B/lane) per G13.
// ---------------------------------------------------------------------------
__global__ __launch_bounds__(256) void gn_apply_t(const float* __restrict__ x,
                                                  const float* __restrict__ stats,
                                                  const float* __restrict__ gw,
                                                  const float* __restrict__ gb,
                                                  u16* __restrict__ Ht) {
    __shared__ float tile[64][65];
    const int b = blockIdx.z, c0 = blockIdx.y * 64, l0 = blockIdx.x * 64;
    const int t = threadIdx.x;
    const int rid = t >> 4, q = t & 15;   // 16 rows x 16 quads per pass
    const float inv = 1.f / (CPG * LEN);
    #pragma unroll
    for (int pass = 0; pass < 4; ++pass) {
        const int c = rid + pass * 16;        // row within tile
        const int ca = c0 + c;                // absolute channel
        const int base = (b * NG + (ca >> 4)) * 4;
        const float S  = stats[base + 0] + stats[base + 1] + stats[base + 2] + stats[base + 3];
        const float S2 = stats[1024 + base + 0] + stats[1024 + base + 1]
                       + stats[1024 + base + 2] + stats[1024 + base + 3];
        const float mean = S * inv;
        const float var  = S2 * inv - mean * mean;
        const float a  = rsqrtf(var + 1e-6f) * gw[ca];
        const float sh = gb[ca] - mean * a;
        const float4 v = *(const float4*)&x[((size_t)b * CH + ca) * LEN + l0 + q * 4];
        tile[c][q * 4 + 0] = v.x * a + sh;
        tile[c][q * 4 + 1] = v.y * a + sh;
        tile[c][q * 4 + 2] = v.z * a + sh;
        tile[c][q * 4 + 3] = v.w * a + sh;
    }
    __syncthreads();
    #pragma unroll
    for (int pass = 0; pass < 4; ++pass) {
        const int l = rid + pass * 16;
        ushort4 o;
        o.x = f2bf(tile[q * 4 + 0][l]);
        o.y = f2bf(tile[q * 4 + 1][l]);
        o.z = f2bf(tile[q * 4 + 2][l]);
        o.w = f2bf(tile[q * 4 + 3][l]);
        *(ushort4*)&Ht[((size_t)b * LEN + l0 + l) * CH + c0 + q * 4] = o;
    }
}

// ---------------------------------------------------------------------------
// MFMA GEMM (B^T form), 128x128 tile, BK=64, mfma_f32_32x32x16_bf16.
// r4 schedule (proven best: single-buffer, 2-barrier, 256 thr / 4 waves,
// 4 blocks/CU via __launch_bounds__(256,4)).
// Bijective XCD remap ONLY on scores (EPI_EXP) — the single remap variant
// the counters endorsed (FETCH 74->27 MB); remap on other GEMMs measured
// net-negative (r8) and stays reverted.
// LDS k-chunks XOR-swizzled by row (chunk stored at c = kc ^ (row&7)) via the
// GLOBAL source address (global_load_lds dest must stay lane-contiguous).
// ---------------------------------------------------------------------------
#define EPI_QK   0   // bf16; (Out,bias)/(Out2,bias2) by m half; +bias[m]
#define EPI_TBN  1   // bf16; +bias[n]
#define EPI_EXP  2   // bf16; exp(acc*alpha), accumulate rowsum[n]; XCD remap
#define EPI_TNRM 3   // bf16; * (1/rowsum[n])
#define EPI_FIN  4   // f32;  +bias[n] + res

template <int MODE>
__global__ __launch_bounds__(256, 4) void gemm_bt(
    const u16* __restrict__ A, int lda, long long sA,
    const u16* __restrict__ B, int ldb, long long sB,
    void* __restrict__ Out, void* __restrict__ Out2,
    int ldo, long long sO,
    const float* __restrict__ bias, const float* __restrict__ bias2,
    const float* __restrict__ res, long long sR,
    float* __restrict__ rsum, long long sRS,
    int K, float alpha) {
    __shared__ u16 As[128 * 64];   // 16 KB
    __shared__ u16 Bs[128 * 64];   // 16 KB

    int bz, by, bx;
    if (MODE == EPI_EXP) {
        const int gx = gridDim.x, gy = gridDim.y;
        int flat = (blockIdx.z * gy + blockIdx.y) * gx + blockIdx.x;
        const int nbk = gx * gy * (int)gridDim.z;
        flat = (flat & 7) * (nbk >> 3) + (flat >> 3);
        bz = flat / (gx * gy);
        const int rr = flat - bz * gx * gy;
        by = rr / gx;
        bx = rr - by * gx;
    } else {
        bz = blockIdx.z; by = blockIdx.y; bx = blockIdx.x;
    }

    const int n0 = bx * 128, m0 = by * 128;
    A += (size_t)bz * sA;
    B += (size_t)bz * sB;
    const int t = threadIdx.x;
    const int lane = t & 63, wid = t >> 6;

    const int rowL = t >> 3, kq = (t & 7) ^ (rowL & 7);
    unsigned aoff = (unsigned)((m0 + rowL) * lda + kq * 8);
    unsigned boff = (unsigned)((n0 + rowL) * ldb + kq * 8);
    u16* const lds_dst_a = As + t * 8;
    u16* const lds_dst_b = Bs + t * 8;

    f32x16 acc[2][2];
    #pragma unroll
    for (int i = 0; i < 2; ++i)
        #pragma unroll
        for (int j = 0; j < 2; ++j)
            acc[i][j] = (f32x16)(0.f);

    const int col = lane & 31, half = lane >> 5;
    const int wm = (wid & 1) * 64, wn = (wid >> 1) * 64;
    const int mf = wm + col, nf = wn + col;
    const int mswz = mf & 7, nswz = nf & 7;

    for (int k0 = 0; k0 < K; k0 += 64) {
        #pragma unroll
        for (int g = 0; g < 4; ++g) {
            gload16(A + aoff + g * (32 * lda), lds_dst_a + g * 2048);
            gload16(B + boff + g * (32 * ldb), lds_dst_b + g * 2048);
        }
        aoff += 64; boff += 64;
        __syncthreads();
        #pragma unroll
        for (int ks = 0; ks < 4; ++ks) {
            const int kcA = ((ks * 2 + half) ^ mswz) * 8;
            const int kcB = ((ks * 2 + half) ^ nswz) * 8;
            bf16x8 a0 = *(const bf16x8*)(As + (mf)      * 64 + kcA);
            bf16x8 a1 = *(const bf16x8*)(As + (mf + 32) * 64 + kcA);
            bf16x8 b0 = *(const bf16x8*)(Bs + (nf)      * 64 + kcB);
            bf16x8 b1 = *(const bf16x8*)(Bs + (nf + 32) * 64 + kcB);
            acc[0][0] = __builtin_amdgcn_mfma_f32_32x32x16_bf16(a0, b0, acc[0][0], 0, 0, 0);
            acc[0][1] = __builtin_amdgcn_mfma_f32_32x32x16_bf16(a0, b1, acc[0][1], 0, 0, 0);
            acc[1][0] = __builtin_amdgcn_mfma_f32_32x32x16_bf16(a1, b0, acc[1][0], 0, 0, 0);
            acc[1][1] = __builtin_amdgcn_mfma_f32_32x32x16_bf16(a1, b1, acc[1][1], 0, 0, 0);
        }
        __syncthreads();
    }

    // C/D: col = lane&31 (n), row = (reg&3) + 8*(reg>>2) + 4*half (+ 32*i_m)
    if (MODE == EPI_FIN) {
        float* O = (float*)Out + (size_t)bz * sO;
        const float* R = res + (size_t)bz * sR;
        #pragma unroll
        for (int im = 0; im < 2; ++im)
            #pragma unroll
            for (int g4 = 0; g4 < 4; ++g4) {
                const int mb = m0 + wm + im * 32 + g4 * 8 + half * 4;
                #pragma unroll
                for (int jn = 0; jn < 2; ++jn) {
                    const int n = n0 + wn + jn * 32 + col;
                    const float bb = bias[n];
                    const size_t base = (size_t)n * ldo + mb;
                    const float4 r4 = *(const float4*)&R[base];
                    float4 o4;
                    o4.x = acc[im][jn][g4 * 4 + 0] + bb + r4.x;
                    o4.y = acc[im][jn][g4 * 4 + 1] + bb + r4.y;
                    o4.z = acc[im][jn][g4 * 4 + 2] + bb + r4.z;
                    o4.w = acc[im][jn][g4 * 4 + 3] + bb + r4.w;
                    *(float4*)&O[base] = o4;
                }
            }
    } else if (MODE == EPI_EXP) {
        u16* O = (u16*)Out + (size_t)bz * sO;
        float* RS = rsum + (size_t)bz * sRS;
        float psum[2] = {0.f, 0.f};
        #pragma unroll
        for (int im = 0; im < 2; ++im)
            #pragma unroll
            for (int g4 = 0; g4 < 4; ++g4) {
                const int mb = m0 + wm + im * 32 + g4 * 8 + half * 4;
                #pragma unroll
                for (int jn = 0; jn < 2; ++jn) {
                    const int n = n0 + wn + jn * 32 + col;
                    u16 h0 = f2bf(__expf(acc[im][jn][g4 * 4 + 0] * alpha));
                    u16 h1 = f2bf(__expf(acc[im][jn][g4 * 4 + 1] * alpha));
                    u16 h2 = f2bf(__expf(acc[im][jn][g4 * 4 + 2] * alpha));
                    u16 h3 = f2bf(__expf(acc[im][jn][g4 * 4 + 3] * alpha));
                    psum[jn] += bf2f(h0) + bf2f(h1) + bf2f(h2) + bf2f(h3);
                    *(ushort4*)&O[(size_t)n * ldo + mb] = make_ushort4(h0, h1, h2, h3);
                }
            }
        #pragma unroll
        for (int jn = 0; jn < 2; ++jn) psum[jn] += __shfl_xor(psum[jn], 32, 64);
        if (half == 0) {
            #pragma unroll
            for (int jn = 0; jn < 2; ++jn)
                atomicAdd(&RS[n0 + wn + jn * 32 + col], psum[jn]);
        }
    } else {
        u16* O;
        const float* bi = bias;
        const float* RS = (MODE == EPI_TNRM) ? rsum + (size_t)bz * sRS : nullptr;
        int mbase = m0 + wm;
        if (MODE == EPI_QK) {
            const bool hi = (m0 & 512) != 0;
            O  = (u16*)(hi ? Out2 : Out) + (size_t)bz * sO;
            bi = hi ? bias2 : bias;
            mbase = (m0 & 511) + wm;
        } else {
            O = (u16*)Out + (size_t)bz * sO;
        }
        float inv[2];
        if (MODE == EPI_TNRM) {
            inv[0] = 1.f / RS[n0 + wn + col];
            inv[1] = 1.f / RS[n0 + wn + 32 + col];
        }
        #pragma unroll
        for (int im = 0; im < 2; ++im)
            #pragma unroll
            for (int g4 = 0; g4 < 4; ++g4) {
                const int mb = mbase + im * 32 + g4 * 8 + half * 4;
                float4 bm = make_float4(0.f, 0.f, 0.f, 0.f);
                if (MODE == EPI_QK) bm = *(const float4*)&bi[mb];
                #pragma unroll
                for (int jn = 0; jn < 2; ++jn) {
                    const int n = n0 + wn + jn * 32 + col;
                    float v0 = acc[im][jn][g4 * 4 + 0];
                    float v1 = acc[im][jn][g4 * 4 + 1];
                    float v2 = acc[im][jn][g4 * 4 + 2];
                    float v3 = acc[im][jn][g4 * 4 + 3];
                    if (MODE == EPI_QK)  { v0 += bm.x; v1 += bm.y; v2 += bm.z; v3 += bm.w; }
                    if (MODE == EPI_TBN) { const float bb = bi[n]; v0 += bb; v1 += bb; v2 += bb; v3 += bb; }
                    if (MODE == EPI_TNRM) { v0 *= inv[jn]; v1 *= inv[jn]; v2 *= inv[jn]; v3 *= inv[jn]; }
                    ushort4 pk = make_ushort4(f2bf(v0), f2bf(v1), f2bf(v2), f2bf(v3));
                    *(ushort4*)&O[(size_t)n * ldo + mb] = pk;
                }
            }
    }
}

// ---------------------------------------------------------------------------
extern "C" void kernel_launch(void* const* d_in, const int* in_sizes, int n_in,
                              void* d_out, int out_size, void* d_ws, size_t ws_size,
                              hipStream_t stream) {
    const float* x    = (const float*)d_in[0];
    const float* gn_w = (const float*)d_in[1];
    const float* gn_b = (const float*)d_in[2];
    const float* wq   = (const float*)d_in[3];
    const float* bq   = (const float*)d_in[4];
    const float* wk   = (const float*)d_in[5];
    const float* bk   = (const float*)d_in[6];
    const float* wv   = (const float*)d_in[7];
    const float* bv   = (const float*)d_in[8];
    const float* wo   = (const float*)d_in[9];
    const float* bo   = (const float*)d_in[10];
    float* out = (float*)d_out;

    char* p = (char*)d_ws;
    const size_t WSZ = (size_t)CH * CH * 2;
    const size_t HSZ = (size_t)BATCH * CH * LEN * 2;
    u16* Wqk = (u16*)p; p += 2 * WSZ;   // rows 0-511 = Wq, 512-1023 = Wk
    u16* Wvb = (u16*)p; p += WSZ;
    u16* Wob = (u16*)p; p += WSZ;
    u16* Ht  = (u16*)p; p += HSZ;   // GN out [b][l][c]; later PV out [b][i][c]
    u16* Qt  = (u16*)p; p += HSZ;   // [b][l][c]
    u16* Kt  = (u16*)p; p += HSZ;   // [b][l][c]
    u16* Vb  = (u16*)p; p += HSZ;   // [b][c][l]
    u16* Sb  = (u16*)p; p += (size_t)BATCH * LEN * LEN * 2;  // exp(scores)
    float* rowsum = (float*)p; p += (size_t)BATCH * LEN * 4; // 16384 f32, zeroed
    float* stats  = (float*)p;      // 2048 f32: S partials [0,1024), S2 [1024,2048)

    const long long sH = (long long)LEN * CH;
    const long long sV = (long long)CH * LEN;
    const long long sS = (long long)LEN * LEN;
    const float scale = 0.04419417382415922f;   // 512^-0.5

    // one pre-pass launch: zero(16) | wconv(1024) | stats partials(1024)
    fused_pre<<<2064, 256, 0, stream>>>(x, wq, wk, wv, wo,
                                        Wqk, Wqk + (size_t)CH * CH, Wvb, Wob,
                                        (float4*)rowsum, stats);
    gn_apply_t<<<dim3(LEN / 64, CH / 64, BATCH), 256, 0, stream>>>(x, stats, gn_w, gn_b, Ht);

    // Q+K fused: A=Wqk (m=o), B=Ht (n=l) -> Qt/Kt[l][o] packed in o
    gemm_bt<EPI_QK><<<dim3(16, 8, 8), 256, 0, stream>>>(
        Wqk, CH, 0, Ht, CH, sH, Qt, Kt, CH, sH, bq, bk, nullptr, 0, nullptr, 0, CH, 0.f);
    // V: A=Ht (m=l), B=Wv (n=c) -> Vb[c][l] packed in l, bias[c]
    gemm_bt<EPI_TBN><<<dim3(4, 16, 8), 256, 0, stream>>>(
        Ht, CH, sH, Wvb, CH, 0, Vb, nullptr, LEN, sV, bv, nullptr, nullptr, 0, nullptr, 0, CH, 0.f);
    // scores: A=Kt (m=j), B=Qt (n=i) -> E[i][j]=exp(scale*S) packed in j, rowsum[i]
    gemm_bt<EPI_EXP><<<dim3(16, 16, 8), 256, 0, stream>>>(
        Kt, CH, sH, Qt, CH, sH, Sb, nullptr, LEN, sS, nullptr, nullptr, nullptr, 0, rowsum, LEN, CH, scale);
    // PV: A=Vb (m=c), B=E (n=i) -> Ht[i][c] packed in c, * 1/rowsum[i]
    gemm_bt<EPI_TNRM><<<dim3(16, 4, 8), 256, 0, stream>>>(
        Vb, LEN, sV, Sb, LEN, sS, Ht, nullptr, CH, sH, nullptr, nullptr, nullptr, 0, rowsum, LEN, LEN, 0.f);
    // final: A=Ht (m=l), B=Wo (n=o) -> out[o][l] f32 + bias[o] + x residual
    gemm_bt<EPI_FIN><<<dim3(4, 16, 8), 256, 0, stream>>>(
        Ht, CH, sH, Wob, CH, 0, out, nullptr, LEN, sV, bo, nullptr, x, sV, nullptr, 0, CH, 0.f);
}

// Round 12
// 265.797 us; speedup vs baseline: 1.7725x; 1.0211x over previous
//
#include <hip/hip_runtime.h>
#include <math.h>

#define BATCH 8
#define CH 512
#define LEN 2048
#define NG 32
#define CPG 16

typedef unsigned short u16;
typedef __bf16 bf16x8 __attribute__((ext_vector_type(8)));
typedef float f32x16 __attribute__((ext_vector_type(16)));

__device__ __forceinline__ u16 f2bf(float f) {
    union { float f; unsigned u; } c; c.f = f;
    unsigned r = c.u + 0x7fffu + ((c.u >> 16) & 1u);   // RNE
    return (u16)(r >> 16);
}
__device__ __forceinline__ float bf2f(u16 h) {
    union { unsigned u; float f; } c; c.u = ((unsigned)h) << 16;
    return c.f;
}
__device__ __forceinline__ void gload16(const u16* g, u16* l) {
    __builtin_amdgcn_global_load_lds(
        (const __attribute__((address_space(1))) unsigned int*)g,
        (__attribute__((address_space(3))) unsigned int*)l, 16, 0, 0);
}

// ---------------------------------------------------------------------------
// fused pre-pass, one launch, 3 independent block ranges:
//  [0,16)       zero rowsum (16 x 256 x float4 = 16384 f32)
//  [16,1040)    weight f32->bf16 conversion (4 x 256 blocks)
//  [1040,2064)  GN stats partials: 4 slots per (b,g), PLAIN stores
// ---------------------------------------------------------------------------
__global__ __launch_bounds__(256) void fused_pre(
    const float* __restrict__ x,
    const float* __restrict__ w0, const float* __restrict__ w1,
    const float* __restrict__ w2, const float* __restrict__ w3,
    u16* __restrict__ o0, u16* __restrict__ o1,
    u16* __restrict__ o2, u16* __restrict__ o3,
    float4* __restrict__ zbuf, float* __restrict__ stats) {
    const int blk = blockIdx.x;
    if (blk < 16) {
        zbuf[blk * 256 + threadIdx.x] = make_float4(0.f, 0.f, 0.f, 0.f);
    } else if (blk < 1040) {
        const int wb = blk - 16;
        const float* s; u16* d;
        switch (wb >> 8) {
            case 0: s = w0; d = o0; break;
            case 1: s = w1; d = o1; break;
            case 2: s = w2; d = o2; break;
            default: s = w3; d = o3; break;
        }
        const int i = (wb & 255) * 256 + threadIdx.x;
        float4 f = ((const float4*)s)[i];
        ((ushort4*)d)[i] = make_ushort4(f2bf(f.x), f2bf(f.y), f2bf(f.z), f2bf(f.w));
    } else {
        const int sb = blk - 1040;
        const int b = sb >> 7, g = (sb >> 2) & 31, sl = sb & 3;
        const float4* xp = (const float4*)(x + ((size_t)b * CH + (size_t)g * CPG) * LEN) + sl * 2048;
        float s = 0.f, s2 = 0.f;
        #pragma unroll
        for (int i = 0; i < 8; ++i) {
            float4 v = xp[threadIdx.x + i * 256];
            s += v.x + v.y + v.z + v.w;
            s2 = fmaf(v.x, v.x, fmaf(v.y, v.y, fmaf(v.z, v.z, fmaf(v.w, v.w, s2))));
        }
        #pragma unroll
        for (int off = 32; off > 0; off >>= 1) {
            s  += __shfl_down(s, off, 64);
            s2 += __shfl_down(s2, off, 64);
        }
        __shared__ float sm[2][4];
        const int lane = threadIdx.x & 63, wv = threadIdx.x >> 6;
        if (lane == 0) { sm[0][wv] = s; sm[1][wv] = s2; }
        __syncthreads();
        if (threadIdx.x == 0) {
            const int base = (b * NG + g) * 4 + sl;
            stats[base]        = sm[0][0] + sm[0][1] + sm[0][2] + sm[0][3];
            stats[1024 + base] = sm[1][0] + sm[1][1] + sm[1][2] + sm[1][3];
        }
    }
}

// ---------------------------------------------------------------------------
// GN apply + [c][l]->[l][c] transpose; affine recomputed from stats partials.
// ---------------------------------------------------------------------------
__global__ __launch_bounds__(256) void gn_apply_t(const float* __restrict__ x,
                                                  const float* __restrict__ stats,
                                                  const float* __restrict__ gw,
                                                  const float* __restrict__ gb,
                                                  u16* __restrict__ Ht) {
    __shared__ float tile[64][65];
    const int b = blockIdx.z, c0 = blockIdx.y * 64, l0 = blockIdx.x * 64;
    const int t = threadIdx.x;
    const int rid = t >> 4, q = t & 15;
    const float inv = 1.f / (CPG * LEN);
    #pragma unroll
    for (int pass = 0; pass < 4; ++pass) {
        const int c = rid + pass * 16;
        const int ca = c0 + c;
        const int base = (b * NG + (ca >> 4)) * 4;
        const float S  = stats[base + 0] + stats[base + 1] + stats[base + 2] + stats[base + 3];
        const float S2 = stats[1024 + base + 0] + stats[1024 + base + 1]
                       + stats[1024 + base + 2] + stats[1024 + base + 3];
        const float mean = S * inv;
        const float var  = S2 * inv - mean * mean;
        const float a  = rsqrtf(var + 1e-6f) * gw[ca];
        const float sh = gb[ca] - mean * a;
        const float4 v = *(const float4*)&x[((size_t)b * CH + ca) * LEN + l0 + q * 4];
        tile[c][q * 4 + 0] = v.x * a + sh;
        tile[c][q * 4 + 1] = v.y * a + sh;
        tile[c][q * 4 + 2] = v.z * a + sh;
        tile[c][q * 4 + 3] = v.w * a + sh;
    }
    __syncthreads();
    #pragma unroll
    for (int pass = 0; pass < 4; ++pass) {
        const int l = rid + pass * 16;
        ushort4 o;
        o.x = f2bf(tile[q * 4 + 0][l]);
        o.y = f2bf(tile[q * 4 + 1][l]);
        o.z = f2bf(tile[q * 4 + 2][l]);
        o.w = f2bf(tile[q * 4 + 3][l]);
        *(ushort4*)&Ht[((size_t)b * LEN + l0 + l) * CH + c0 + q * 4] = o;
    }
}

// ---------------------------------------------------------------------------
// r4 GEMM core (proven): 128x128 tile, BK=64, single-buffer, 2-barrier,
// 256 thr / 4 waves, 4 blocks/CU. XOR-swizzled k-chunks via global source.
// ---------------------------------------------------------------------------
#define EPI_QK   0
#define EPI_TNRM 3
#define EPI_FIN  4

template <int MODE>
__global__ __launch_bounds__(256, 4) void gemm_bt(
    const u16* __restrict__ A, int lda, long long sA,
    const u16* __restrict__ B, int ldb, long long sB,
    void* __restrict__ Out, void* __restrict__ Out2,
    int ldo, long long sO,
    const float* __restrict__ bias, const float* __restrict__ bias2,
    const float* __restrict__ res, long long sR,
    float* __restrict__ rsum, long long sRS,
    int K, float alpha) {
    __shared__ u16 As[128 * 64];
    __shared__ u16 Bs[128 * 64];

    const int bz = blockIdx.z, by = blockIdx.y, bx = blockIdx.x;
    const int n0 = bx * 128, m0 = by * 128;
    A += (size_t)bz * sA;
    B += (size_t)bz * sB;
    const int t = threadIdx.x;
    const int lane = t & 63, wid = t >> 6;

    const int rowL = t >> 3, kq = (t & 7) ^ (rowL & 7);
    unsigned aoff = (unsigned)((m0 + rowL) * lda + kq * 8);
    unsigned boff = (unsigned)((n0 + rowL) * ldb + kq * 8);
    u16* const lds_dst_a = As + t * 8;
    u16* const lds_dst_b = Bs + t * 8;

    f32x16 acc[2][2];
    #pragma unroll
    for (int i = 0; i < 2; ++i)
        #pragma unroll
        for (int j = 0; j < 2; ++j)
            acc[i][j] = (f32x16)(0.f);

    const int col = lane & 31, half = lane >> 5;
    const int wm = (wid & 1) * 64, wn = (wid >> 1) * 64;
    const int mf = wm + col, nf = wn + col;
    const int mswz = mf & 7, nswz = nf & 7;

    for (int k0 = 0; k0 < K; k0 += 64) {
        #pragma unroll
        for (int g = 0; g < 4; ++g) {
            gload16(A + aoff + g * (32 * lda), lds_dst_a + g * 2048);
            gload16(B + boff + g * (32 * ldb), lds_dst_b + g * 2048);
        }
        aoff += 64; boff += 64;
        __syncthreads();
        #pragma unroll
        for (int ks = 0; ks < 4; ++ks) {
            const int kcA = ((ks * 2 + half) ^ mswz) * 8;
            const int kcB = ((ks * 2 + half) ^ nswz) * 8;
            bf16x8 a0 = *(const bf16x8*)(As + (mf)      * 64 + kcA);
            bf16x8 a1 = *(const bf16x8*)(As + (mf + 32) * 64 + kcA);
            bf16x8 b0 = *(const bf16x8*)(Bs + (nf)      * 64 + kcB);
            bf16x8 b1 = *(const bf16x8*)(Bs + (nf + 32) * 64 + kcB);
            acc[0][0] = __builtin_amdgcn_mfma_f32_32x32x16_bf16(a0, b0, acc[0][0], 0, 0, 0);
            acc[0][1] = __builtin_amdgcn_mfma_f32_32x32x16_bf16(a0, b1, acc[0][1], 0, 0, 0);
            acc[1][0] = __builtin_amdgcn_mfma_f32_32x32x16_bf16(a1, b0, acc[1][0], 0, 0, 0);
            acc[1][1] = __builtin_amdgcn_mfma_f32_32x32x16_bf16(a1, b1, acc[1][1], 0, 0, 0);
        }
        __syncthreads();
    }

    // C/D: col = lane&31 (n), row = (reg&3) + 8*(reg>>2) + 4*half (+ 32*i_m)
    if (MODE == EPI_FIN) {
        float* O = (float*)Out + (size_t)bz * sO;
        const float* R = res + (size_t)bz * sR;
        #pragma unroll
        for (int im = 0; im < 2; ++im)
            #pragma unroll
            for (int g4 = 0; g4 < 4; ++g4) {
                const int mb = m0 + wm + im * 32 + g4 * 8 + half * 4;
                #pragma unroll
                for (int jn = 0; jn < 2; ++jn) {
                    const int n = n0 + wn + jn * 32 + col;
                    const float bb = bias[n];
                    const size_t base = (size_t)n * ldo + mb;
                    const float4 r4 = *(const float4*)&R[base];
                    float4 o4;
                    o4.x = acc[im][jn][g4 * 4 + 0] + bb + r4.x;
                    o4.y = acc[im][jn][g4 * 4 + 1] + bb + r4.y;
                    o4.z = acc[im][jn][g4 * 4 + 2] + bb + r4.z;
                    o4.w = acc[im][jn][g4 * 4 + 3] + bb + r4.w;
                    *(float4*)&O[base] = o4;
                }
            }
    } else {
        u16* O;
        const float* bi = bias;
        const float* RS = (MODE == EPI_TNRM) ? rsum + (size_t)bz * sRS : nullptr;
        int mbase = m0 + wm;
        if (MODE == EPI_QK) {
            const bool hi = (m0 & 512) != 0;
            O  = (u16*)(hi ? Out2 : Out) + (size_t)bz * sO;
            bi = hi ? bias2 : bias;
            mbase = (m0 & 511) + wm;
        } else {
            O = (u16*)Out + (size_t)bz * sO;
        }
        float inv[2];
        if (MODE == EPI_TNRM) {
            inv[0] = 1.f / RS[n0 + wn + col];
            inv[1] = 1.f / RS[n0 + wn + 32 + col];
        }
        #pragma unroll
        for (int im = 0; im < 2; ++im)
            #pragma unroll
            for (int g4 = 0; g4 < 4; ++g4) {
                const int mb = mbase + im * 32 + g4 * 8 + half * 4;
                float4 bm = make_float4(0.f, 0.f, 0.f, 0.f);
                if (MODE == EPI_QK) bm = *(const float4*)&bi[mb];
                #pragma unroll
                for (int jn = 0; jn < 2; ++jn) {
                    const int n = n0 + wn + jn * 32 + col;
                    float v0 = acc[im][jn][g4 * 4 + 0];
                    float v1 = acc[im][jn][g4 * 4 + 1];
                    float v2 = acc[im][jn][g4 * 4 + 2];
                    float v3 = acc[im][jn][g4 * 4 + 3];
                    if (MODE == EPI_QK)  { v0 += bm.x; v1 += bm.y; v2 += bm.z; v3 += bm.w; }
                    if (MODE == EPI_TNRM) { v0 *= inv[jn]; v1 *= inv[jn]; v2 *= inv[jn]; v3 *= inv[jn]; }
                    ushort4 pk = make_ushort4(f2bf(v0), f2bf(v1), f2bf(v2), f2bf(v3));
                    *(ushort4*)&O[(size_t)n * ldo + mb] = pk;
                }
            }
    }
}

// ---------------------------------------------------------------------------
// Round-12 (= round-11 resubmit): scores + V in ONE launch (2560 blocks).
// Both GEMMs share the r4 core geometry exactly (lda=ldb=CH, ldo=LEN, K=512,
// 128^2 tiles); block-uniform runtime branch selects operands + epilogue.
//  blocks [0,2048):   scores  A=Kt B=Qt -> Sb=exp(scale*S), rowsum atomics,
//                     with the proven bijective XCD remap.
//  blocks [2048,2560): V      A=Ht B=Wvb -> Vb[c][l] + bias[c].
// V is independent of scores but must precede PV: stream ordering after this
// launch guarantees it. V's 512 blocks backfill scores' dispatch tail ->
// V's serial time (~15us + gap) is mostly hidden.
// ---------------------------------------------------------------------------
__global__ __launch_bounds__(256, 4) void gemm_sv(
    const u16* __restrict__ Kt, const u16* __restrict__ Qt,
    const u16* __restrict__ Ht, const u16* __restrict__ Wvb,
    u16* __restrict__ Sb, u16* __restrict__ Vb,
    const float* __restrict__ bv, float* __restrict__ rowsum,
    float alpha) {
    __shared__ u16 As[128 * 64];
    __shared__ u16 Bs[128 * 64];

    const long long sH = (long long)LEN * CH;
    const int blk = blockIdx.x;
    const bool isV = blk >= 2048;
    int bz, by, bx;
    const u16 *A, *B;
    u16* O;
    if (!isV) {
        int flat = (blk & 7) * 256 + (blk >> 3);   // bijective XCD remap
        bz = flat >> 8;
        const int rr = flat & 255;
        by = rr >> 4; bx = rr & 15;
        A = Kt + (size_t)bz * sH;
        B = Qt + (size_t)bz * sH;
        O = Sb + (size_t)bz * ((long long)LEN * LEN);
    } else {
        const int v = blk - 2048;
        bz = v >> 6;
        const int rr = v & 63;
        by = rr >> 2; bx = rr & 3;
        A = Ht + (size_t)bz * sH;
        B = Wvb;
        O = Vb + (size_t)bz * ((long long)CH * LEN);
    }

    const int n0 = bx * 128, m0 = by * 128;
    const int t = threadIdx.x;
    const int lane = t & 63, wid = t >> 6;

    const int rowL = t >> 3, kq = (t & 7) ^ (rowL & 7);
    unsigned aoff = (unsigned)((m0 + rowL) * CH + kq * 8);
    unsigned boff = (unsigned)((n0 + rowL) * CH + kq * 8);
    u16* const lds_dst_a = As + t * 8;
    u16* const lds_dst_b = Bs + t * 8;

    f32x16 acc[2][2];
    #pragma unroll
    for (int i = 0; i < 2; ++i)
        #pragma unroll
        for (int j = 0; j < 2; ++j)
            acc[i][j] = (f32x16)(0.f);

    const int col = lane & 31, half = lane >> 5;
    const int wm = (wid & 1) * 64, wn = (wid >> 1) * 64;
    const int mf = wm + col, nf = wn + col;
    const int mswz = mf & 7, nswz = nf & 7;

    for (int k0 = 0; k0 < CH; k0 += 64) {
        #pragma unroll
        for (int g = 0; g < 4; ++g) {
            gload16(A + aoff + g * (32 * CH), lds_dst_a + g * 2048);
            gload16(B + boff + g * (32 * CH), lds_dst_b + g * 2048);
        }
        aoff += 64; boff += 64;
        __syncthreads();
        #pragma unroll
        for (int ks = 0; ks < 4; ++ks) {
            const int kcA = ((ks * 2 + half) ^ mswz) * 8;
            const int kcB = ((ks * 2 + half) ^ nswz) * 8;
            bf16x8 a0 = *(const bf16x8*)(As + (mf)      * 64 + kcA);
            bf16x8 a1 = *(const bf16x8*)(As + (mf + 32) * 64 + kcA);
            bf16x8 b0 = *(const bf16x8*)(Bs + (nf)      * 64 + kcB);
            bf16x8 b1 = *(const bf16x8*)(Bs + (nf + 32) * 64 + kcB);
            acc[0][0] = __builtin_amdgcn_mfma_f32_32x32x16_bf16(a0, b0, acc[0][0], 0, 0, 0);
            acc[0][1] = __builtin_amdgcn_mfma_f32_32x32x16_bf16(a0, b1, acc[0][1], 0, 0, 0);
            acc[1][0] = __builtin_amdgcn_mfma_f32_32x32x16_bf16(a1, b0, acc[1][0], 0, 0, 0);
            acc[1][1] = __builtin_amdgcn_mfma_f32_32x32x16_bf16(a1, b1, acc[1][1], 0, 0, 0);
        }
        __syncthreads();
    }

    if (!isV) {
        float* RS = rowsum + (size_t)bz * LEN;
        float psum[2] = {0.f, 0.f};
        #pragma unroll
        for (int im = 0; im < 2; ++im)
            #pragma unroll
            for (int g4 = 0; g4 < 4; ++g4) {
                const int mb = m0 + wm + im * 32 + g4 * 8 + half * 4;
                #pragma unroll
                for (int jn = 0; jn < 2; ++jn) {
                    const int n = n0 + wn + jn * 32 + col;
                    u16 h0 = f2bf(__expf(acc[im][jn][g4 * 4 + 0] * alpha));
                    u16 h1 = f2bf(__expf(acc[im][jn][g4 * 4 + 1] * alpha));
                    u16 h2 = f2bf(__expf(acc[im][jn][g4 * 4 + 2] * alpha));
                    u16 h3 = f2bf(__expf(acc[im][jn][g4 * 4 + 3] * alpha));
                    psum[jn] += bf2f(h0) + bf2f(h1) + bf2f(h2) + bf2f(h3);
                    *(ushort4*)&O[(size_t)n * LEN + mb] = make_ushort4(h0, h1, h2, h3);
                }
            }
        #pragma unroll
        for (int jn = 0; jn < 2; ++jn) psum[jn] += __shfl_xor(psum[jn], 32, 64);
        if (half == 0) {
            #pragma unroll
            for (int jn = 0; jn < 2; ++jn)
                atomicAdd(&RS[n0 + wn + jn * 32 + col], psum[jn]);
        }
    } else {
        #pragma unroll
        for (int im = 0; im < 2; ++im)
            #pragma unroll
            for (int g4 = 0; g4 < 4; ++g4) {
                const int mb = m0 + wm + im * 32 + g4 * 8 + half * 4;
                #pragma unroll
                for (int jn = 0; jn < 2; ++jn) {
                    const int n = n0 + wn + jn * 32 + col;
                    const float bb = bv[n];
                    ushort4 pk = make_ushort4(f2bf(acc[im][jn][g4 * 4 + 0] + bb),
                                              f2bf(acc[im][jn][g4 * 4 + 1] + bb),
                                              f2bf(acc[im][jn][g4 * 4 + 2] + bb),
                                              f2bf(acc[im][jn][g4 * 4 + 3] + bb));
                    *(ushort4*)&O[(size_t)n * LEN + mb] = pk;
                }
            }
    }
}

// ---------------------------------------------------------------------------
extern "C" void kernel_launch(void* const* d_in, const int* in_sizes, int n_in,
                              void* d_out, int out_size, void* d_ws, size_t ws_size,
                              hipStream_t stream) {
    const float* x    = (const float*)d_in[0];
    const float* gn_w = (const float*)d_in[1];
    const float* gn_b = (const float*)d_in[2];
    const float* wq   = (const float*)d_in[3];
    const float* bq   = (const float*)d_in[4];
    const float* wk   = (const float*)d_in[5];
    const float* bk   = (const float*)d_in[6];
    const float* wv   = (const float*)d_in[7];
    const float* bv   = (const float*)d_in[8];
    const float* wo   = (const float*)d_in[9];
    const float* bo   = (const float*)d_in[10];
    float* out = (float*)d_out;

    char* p = (char*)d_ws;
    const size_t WSZ = (size_t)CH * CH * 2;
    const size_t HSZ = (size_t)BATCH * CH * LEN * 2;
    u16* Wqk = (u16*)p; p += 2 * WSZ;   // rows 0-511 = Wq, 512-1023 = Wk
    u16* Wvb = (u16*)p; p += WSZ;
    u16* Wob = (u16*)p; p += WSZ;
    u16* Ht  = (u16*)p; p += HSZ;   // GN out [b][l][c]; later PV out [b][i][c]
    u16* Qt  = (u16*)p; p += HSZ;   // [b][l][c]
    u16* Kt  = (u16*)p; p += HSZ;   // [b][l][c]
    u16* Vb  = (u16*)p; p += HSZ;   // [b][c][l]
    u16* Sb  = (u16*)p; p += (size_t)BATCH * LEN * LEN * 2;  // exp(scores)
    float* rowsum = (float*)p; p += (size_t)BATCH * LEN * 4; // 16384 f32, zeroed
    float* stats  = (float*)p;      // 2048 f32: S partials | S2 partials

    const long long sH = (long long)LEN * CH;
    const long long sV = (long long)CH * LEN;
    const float scale = 0.04419417382415922f;   // 512^-0.5

    // one pre-pass launch: zero(16) | wconv(1024) | stats partials(1024)
    fused_pre<<<2064, 256, 0, stream>>>(x, wq, wk, wv, wo,
                                        Wqk, Wqk + (size_t)CH * CH, Wvb, Wob,
                                        (float4*)rowsum, stats);
    gn_apply_t<<<dim3(LEN / 64, CH / 64, BATCH), 256, 0, stream>>>(x, stats, gn_w, gn_b, Ht);

    // Q+K fused: A=Wqk (m=o), B=Ht (n=l) -> Qt/Kt[l][o] packed in o
    gemm_bt<EPI_QK><<<dim3(16, 8, 8), 256, 0, stream>>>(
        Wqk, CH, 0, Ht, CH, sH, Qt, Kt, CH, sH, bq, bk, nullptr, 0, nullptr, 0, CH, 0.f);
    // scores (2048 blocks, XCD-remapped) + V (512 blocks) in one launch
    gemm_sv<<<2560, 256, 0, stream>>>(Kt, Qt, Ht, Wvb, Sb, Vb, bv, rowsum, scale);
    // PV: A=Vb (m=c), B=E (n=i) -> Ht[i][c] packed in c, * 1/rowsum[i]
    gemm_bt<EPI_TNRM><<<dim3(16, 4, 8), 256, 0, stream>>>(
        Vb, LEN, sV, Sb, LEN, (long long)LEN * LEN, Ht, nullptr, CH, sH,
        nullptr, nullptr, nullptr, 0, rowsum, LEN, LEN, 0.f);
    // final: A=Ht (m=l), B=Wo (n=o) -> out[o][l] f32 + bias[o] + x residual
    gemm_bt<EPI_FIN><<<dim3(4, 16, 8), 256, 0, stream>>>(
        Ht, CH, sH, Wob, CH, 0, out, nullptr, LEN, sV, bo, nullptr, x, sV, nullptr, 0, CH, 0.f);
}

// Round 13
// 264.476 us; speedup vs baseline: 1.7813x; 1.0050x over previous
//
#include <hip/hip_runtime.h>
#include <math.h>

#define BATCH 8
#define CH 512
#define LEN 2048
#define NG 32
#define CPG 16

typedef unsigned short u16;
typedef __bf16 bf16x8 __attribute__((ext_vector_type(8)));
typedef float f32x16 __attribute__((ext_vector_type(16)));

__device__ __forceinline__ u16 f2bf(float f) {
    union { float f; unsigned u; } c; c.f = f;
    unsigned r = c.u + 0x7fffu + ((c.u >> 16) & 1u);   // RNE
    return (u16)(r >> 16);
}
__device__ __forceinline__ float bf2f(u16 h) {
    union { unsigned u; float f; } c; c.u = ((unsigned)h) << 16;
    return c.f;
}
__device__ __forceinline__ void gload16(const u16* g, u16* l) {
    __builtin_amdgcn_global_load_lds(
        (const __attribute__((address_space(1))) unsigned int*)g,
        (__attribute__((address_space(3))) unsigned int*)l, 16, 0, 0);
}

// ---------------------------------------------------------------------------
// fused pre-pass, one launch, 3 independent block ranges:
//  [0,16)       zero rowsum (16 x 256 x float4 = 16384 f32)
//  [16,1040)    weight f32->bf16 conversion (4 x 256 blocks)
//  [1040,2064)  GN stats partials: 4 slots per (b,g), PLAIN stores
// ---------------------------------------------------------------------------
__global__ __launch_bounds__(256) void fused_pre(
    const float* __restrict__ x,
    const float* __restrict__ w0, const float* __restrict__ w1,
    const float* __restrict__ w2, const float* __restrict__ w3,
    u16* __restrict__ o0, u16* __restrict__ o1,
    u16* __restrict__ o2, u16* __restrict__ o3,
    float4* __restrict__ zbuf, float* __restrict__ stats) {
    const int blk = blockIdx.x;
    if (blk < 16) {
        zbuf[blk * 256 + threadIdx.x] = make_float4(0.f, 0.f, 0.f, 0.f);
    } else if (blk < 1040) {
        const int wb = blk - 16;
        const float* s; u16* d;
        switch (wb >> 8) {
            case 0: s = w0; d = o0; break;
            case 1: s = w1; d = o1; break;
            case 2: s = w2; d = o2; break;
            default: s = w3; d = o3; break;
        }
        const int i = (wb & 255) * 256 + threadIdx.x;
        float4 f = ((const float4*)s)[i];
        ((ushort4*)d)[i] = make_ushort4(f2bf(f.x), f2bf(f.y), f2bf(f.z), f2bf(f.w));
    } else {
        const int sb = blk - 1040;
        const int b = sb >> 7, g = (sb >> 2) & 31, sl = sb & 3;
        const float4* xp = (const float4*)(x + ((size_t)b * CH + (size_t)g * CPG) * LEN) + sl * 2048;
        float s = 0.f, s2 = 0.f;
        #pragma unroll
        for (int i = 0; i < 8; ++i) {
            float4 v = xp[threadIdx.x + i * 256];
            s += v.x + v.y + v.z + v.w;
            s2 = fmaf(v.x, v.x, fmaf(v.y, v.y, fmaf(v.z, v.z, fmaf(v.w, v.w, s2))));
        }
        #pragma unroll
        for (int off = 32; off > 0; off >>= 1) {
            s  += __shfl_down(s, off, 64);
            s2 += __shfl_down(s2, off, 64);
        }
        __shared__ float sm[2][4];
        const int lane = threadIdx.x & 63, wv = threadIdx.x >> 6;
        if (lane == 0) { sm[0][wv] = s; sm[1][wv] = s2; }
        __syncthreads();
        if (threadIdx.x == 0) {
            const int base = (b * NG + g) * 4 + sl;
            stats[base]        = sm[0][0] + sm[0][1] + sm[0][2] + sm[0][3];
            stats[1024 + base] = sm[1][0] + sm[1][1] + sm[1][2] + sm[1][3];
        }
    }
}

// ---------------------------------------------------------------------------
// GN apply + [c][l]->[l][c] transpose; affine recomputed from stats partials.
// ---------------------------------------------------------------------------
__global__ __launch_bounds__(256) void gn_apply_t(const float* __restrict__ x,
                                                  const float* __restrict__ stats,
                                                  const float* __restrict__ gw,
                                                  const float* __restrict__ gb,
                                                  u16* __restrict__ Ht) {
    __shared__ float tile[64][65];
    const int b = blockIdx.z, c0 = blockIdx.y * 64, l0 = blockIdx.x * 64;
    const int t = threadIdx.x;
    const int rid = t >> 4, q = t & 15;
    const float inv = 1.f / (CPG * LEN);
    #pragma unroll
    for (int pass = 0; pass < 4; ++pass) {
        const int c = rid + pass * 16;
        const int ca = c0 + c;
        const int base = (b * NG + (ca >> 4)) * 4;
        const float S  = stats[base + 0] + stats[base + 1] + stats[base + 2] + stats[base + 3];
        const float S2 = stats[1024 + base + 0] + stats[1024 + base + 1]
                       + stats[1024 + base + 2] + stats[1024 + base + 3];
        const float mean = S * inv;
        const float var  = S2 * inv - mean * mean;
        const float a  = rsqrtf(var + 1e-6f) * gw[ca];
        const float sh = gb[ca] - mean * a;
        const float4 v = *(const float4*)&x[((size_t)b * CH + ca) * LEN + l0 + q * 4];
        tile[c][q * 4 + 0] = v.x * a + sh;
        tile[c][q * 4 + 1] = v.y * a + sh;
        tile[c][q * 4 + 2] = v.z * a + sh;
        tile[c][q * 4 + 3] = v.w * a + sh;
    }
    __syncthreads();
    #pragma unroll
    for (int pass = 0; pass < 4; ++pass) {
        const int l = rid + pass * 16;
        ushort4 o;
        o.x = f2bf(tile[q * 4 + 0][l]);
        o.y = f2bf(tile[q * 4 + 1][l]);
        o.z = f2bf(tile[q * 4 + 2][l]);
        o.w = f2bf(tile[q * 4 + 3][l]);
        *(ushort4*)&Ht[((size_t)b * LEN + l0 + l) * CH + c0 + q * 4] = o;
    }
}

// ---------------------------------------------------------------------------
// r4 GEMM core (proven): 128x128 tile, BK=64, single-buffer, 2-barrier,
// 256 thr / 4 waves, 4 blocks/CU. XOR-swizzled k-chunks via global source.
// Round-13: EPI_TNRM (PV) gets bijective XCD remap + m(by)-fast in-XCD
// order. Rationale: PV has NO cross-batch-shared operand (Vb, Sb are
// per-batch), so the r8 damage mechanism (remap destroying cross-batch
// weight-panel reuse in QK/V/FIN) does not apply. Batch->XCD matches the
// scores remap in gemm_sv, so batch b's Sb is read from the XCD that wrote
// it; m-fast groups the 4 c-tiles sharing one Sb i-panel (512KB, L2-fit
// with Vb's 2MB). QK/FIN keep natural order (weight panels shared across
// batches must stay interleaved).
// ---------------------------------------------------------------------------
#define EPI_QK   0
#define EPI_TNRM 3
#define EPI_FIN  4

template <int MODE>
__global__ __launch_bounds__(256, 4) void gemm_bt(
    const u16* __restrict__ A, int lda, long long sA,
    const u16* __restrict__ B, int ldb, long long sB,
    void* __restrict__ Out, void* __restrict__ Out2,
    int ldo, long long sO,
    const float* __restrict__ bias, const float* __restrict__ bias2,
    const float* __restrict__ res, long long sR,
    float* __restrict__ rsum, long long sRS,
    int K, float alpha) {
    __shared__ u16 As[128 * 64];
    __shared__ u16 Bs[128 * 64];

    int bz, by, bx;
    if (MODE == EPI_TNRM) {
        // bijective remap (grid 16x4x8 = 512): XCD k -> batch k; within a
        // batch, by(m)-fast so 4 consecutive-on-XCD blocks share an Sb
        // i-panel.
        const int gx = gridDim.x, gy = gridDim.y;          // 16, 4
        int flat = (blockIdx.z * gy + blockIdx.y) * gx + blockIdx.x;
        const int nbk = gx * gy * (int)gridDim.z;          // 512
        flat = (flat & 7) * (nbk >> 3) + (flat >> 3);      // [xcd]*64 + local
        bz = flat / (gx * gy);
        const int rr = flat - bz * gx * gy;                // [0,64)
        by = rr & 3;                                       // m-fast
        bx = rr >> 2;
    } else {
        bz = blockIdx.z; by = blockIdx.y; bx = blockIdx.x;
    }
    const int n0 = bx * 128, m0 = by * 128;
    A += (size_t)bz * sA;
    B += (size_t)bz * sB;
    const int t = threadIdx.x;
    const int lane = t & 63, wid = t >> 6;

    const int rowL = t >> 3, kq = (t & 7) ^ (rowL & 7);
    unsigned aoff = (unsigned)((m0 + rowL) * lda + kq * 8);
    unsigned boff = (unsigned)((n0 + rowL) * ldb + kq * 8);
    u16* const lds_dst_a = As + t * 8;
    u16* const lds_dst_b = Bs + t * 8;

    f32x16 acc[2][2];
    #pragma unroll
    for (int i = 0; i < 2; ++i)
        #pragma unroll
        for (int j = 0; j < 2; ++j)
            acc[i][j] = (f32x16)(0.f);

    const int col = lane & 31, half = lane >> 5;
    const int wm = (wid & 1) * 64, wn = (wid >> 1) * 64;
    const int mf = wm + col, nf = wn + col;
    const int mswz = mf & 7, nswz = nf & 7;

    for (int k0 = 0; k0 < K; k0 += 64) {
        #pragma unroll
        for (int g = 0; g < 4; ++g) {
            gload16(A + aoff + g * (32 * lda), lds_dst_a + g * 2048);
            gload16(B + boff + g * (32 * ldb), lds_dst_b + g * 2048);
        }
        aoff += 64; boff += 64;
        __syncthreads();
        #pragma unroll
        for (int ks = 0; ks < 4; ++ks) {
            const int kcA = ((ks * 2 + half) ^ mswz) * 8;
            const int kcB = ((ks * 2 + half) ^ nswz) * 8;
            bf16x8 a0 = *(const bf16x8*)(As + (mf)      * 64 + kcA);
            bf16x8 a1 = *(const bf16x8*)(As + (mf + 32) * 64 + kcA);
            bf16x8 b0 = *(const bf16x8*)(Bs + (nf)      * 64 + kcB);
            bf16x8 b1 = *(const bf16x8*)(Bs + (nf + 32) * 64 + kcB);
            acc[0][0] = __builtin_amdgcn_mfma_f32_32x32x16_bf16(a0, b0, acc[0][0], 0, 0, 0);
            acc[0][1] = __builtin_amdgcn_mfma_f32_32x32x16_bf16(a0, b1, acc[0][1], 0, 0, 0);
            acc[1][0] = __builtin_amdgcn_mfma_f32_32x32x16_bf16(a1, b0, acc[1][0], 0, 0, 0);
            acc[1][1] = __builtin_amdgcn_mfma_f32_32x32x16_bf16(a1, b1, acc[1][1], 0, 0, 0);
        }
        __syncthreads();
    }

    // C/D: col = lane&31 (n), row = (reg&3) + 8*(reg>>2) + 4*half (+ 32*i_m)
    if (MODE == EPI_FIN) {
        float* O = (float*)Out + (size_t)bz * sO;
        const float* R = res + (size_t)bz * sR;
        #pragma unroll
        for (int im = 0; im < 2; ++im)
            #pragma unroll
            for (int g4 = 0; g4 < 4; ++g4) {
                const int mb = m0 + wm + im * 32 + g4 * 8 + half * 4;
                #pragma unroll
                for (int jn = 0; jn < 2; ++jn) {
                    const int n = n0 + wn + jn * 32 + col;
                    const float bb = bias[n];
                    const size_t base = (size_t)n * ldo + mb;
                    const float4 r4 = *(const float4*)&R[base];
                    float4 o4;
                    o4.x = acc[im][jn][g4 * 4 + 0] + bb + r4.x;
                    o4.y = acc[im][jn][g4 * 4 + 1] + bb + r4.y;
                    o4.z = acc[im][jn][g4 * 4 + 2] + bb + r4.z;
                    o4.w = acc[im][jn][g4 * 4 + 3] + bb + r4.w;
                    *(float4*)&O[base] = o4;
                }
            }
    } else {
        u16* O;
        const float* bi = bias;
        const float* RS = (MODE == EPI_TNRM) ? rsum + (size_t)bz * sRS : nullptr;
        int mbase = m0 + wm;
        if (MODE == EPI_QK) {
            const bool hi = (m0 & 512) != 0;
            O  = (u16*)(hi ? Out2 : Out) + (size_t)bz * sO;
            bi = hi ? bias2 : bias;
            mbase = (m0 & 511) + wm;
        } else {
            O = (u16*)Out + (size_t)bz * sO;
        }
        float inv[2];
        if (MODE == EPI_TNRM) {
            inv[0] = 1.f / RS[n0 + wn + col];
            inv[1] = 1.f / RS[n0 + wn + 32 + col];
        }
        #pragma unroll
        for (int im = 0; im < 2; ++im)
            #pragma unroll
            for (int g4 = 0; g4 < 4; ++g4) {
                const int mb = mbase + im * 32 + g4 * 8 + half * 4;
                float4 bm = make_float4(0.f, 0.f, 0.f, 0.f);
                if (MODE == EPI_QK) bm = *(const float4*)&bi[mb];
                #pragma unroll
                for (int jn = 0; jn < 2; ++jn) {
                    const int n = n0 + wn + jn * 32 + col;
                    float v0 = acc[im][jn][g4 * 4 + 0];
                    float v1 = acc[im][jn][g4 * 4 + 1];
                    float v2 = acc[im][jn][g4 * 4 + 2];
                    float v3 = acc[im][jn][g4 * 4 + 3];
                    if (MODE == EPI_QK)  { v0 += bm.x; v1 += bm.y; v2 += bm.z; v3 += bm.w; }
                    if (MODE == EPI_TNRM) { v0 *= inv[jn]; v1 *= inv[jn]; v2 *= inv[jn]; v3 *= inv[jn]; }
                    ushort4 pk = make_ushort4(f2bf(v0), f2bf(v1), f2bf(v2), f2bf(v3));
                    *(ushort4*)&O[(size_t)n * ldo + mb] = pk;
                }
            }
    }
}

// ---------------------------------------------------------------------------
// scores + V in ONE launch (2560 blocks), r12-proven.
//  blocks [0,2048):   scores  A=Kt B=Qt -> Sb=exp(scale*S), rowsum atomics,
//                     bijective XCD remap (batch->XCD).
//  blocks [2048,2560): V      A=Ht B=Wvb -> Vb[c][l] + bias[c].
// ---------------------------------------------------------------------------
__global__ __launch_bounds__(256, 4) void gemm_sv(
    const u16* __restrict__ Kt, const u16* __restrict__ Qt,
    const u16* __restrict__ Ht, const u16* __restrict__ Wvb,
    u16* __restrict__ Sb, u16* __restrict__ Vb,
    const float* __restrict__ bv, float* __restrict__ rowsum,
    float alpha) {
    __shared__ u16 As[128 * 64];
    __shared__ u16 Bs[128 * 64];

    const long long sH = (long long)LEN * CH;
    const int blk = blockIdx.x;
    const bool isV = blk >= 2048;
    int bz, by, bx;
    const u16 *A, *B;
    u16* O;
    if (!isV) {
        int flat = (blk & 7) * 256 + (blk >> 3);   // bijective XCD remap
        bz = flat >> 8;
        const int rr = flat & 255;
        by = rr >> 4; bx = rr & 15;
        A = Kt + (size_t)bz * sH;
        B = Qt + (size_t)bz * sH;
        O = Sb + (size_t)bz * ((long long)LEN * LEN);
    } else {
        const int v = blk - 2048;
        bz = v >> 6;
        const int rr = v & 63;
        by = rr >> 2; bx = rr & 3;
        A = Ht + (size_t)bz * sH;
        B = Wvb;
        O = Vb + (size_t)bz * ((long long)CH * LEN);
    }

    const int n0 = bx * 128, m0 = by * 128;
    const int t = threadIdx.x;
    const int lane = t & 63, wid = t >> 6;

    const int rowL = t >> 3, kq = (t & 7) ^ (rowL & 7);
    unsigned aoff = (unsigned)((m0 + rowL) * CH + kq * 8);
    unsigned boff = (unsigned)((n0 + rowL) * CH + kq * 8);
    u16* const lds_dst_a = As + t * 8;
    u16* const lds_dst_b = Bs + t * 8;

    f32x16 acc[2][2];
    #pragma unroll
    for (int i = 0; i < 2; ++i)
        #pragma unroll
        for (int j = 0; j < 2; ++j)
            acc[i][j] = (f32x16)(0.f);

    const int col = lane & 31, half = lane >> 5;
    const int wm = (wid & 1) * 64, wn = (wid >> 1) * 64;
    const int mf = wm + col, nf = wn + col;
    const int mswz = mf & 7, nswz = nf & 7;

    for (int k0 = 0; k0 < CH; k0 += 64) {
        #pragma unroll
        for (int g = 0; g < 4; ++g) {
            gload16(A + aoff + g * (32 * CH), lds_dst_a + g * 2048);
            gload16(B + boff + g * (32 * CH), lds_dst_b + g * 2048);
        }
        aoff += 64; boff += 64;
        __syncthreads();
        #pragma unroll
        for (int ks = 0; ks < 4; ++ks) {
            const int kcA = ((ks * 2 + half) ^ mswz) * 8;
            const int kcB = ((ks * 2 + half) ^ nswz) * 8;
            bf16x8 a0 = *(const bf16x8*)(As + (mf)      * 64 + kcA);
            bf16x8 a1 = *(const bf16x8*)(As + (mf + 32) * 64 + kcA);
            bf16x8 b0 = *(const bf16x8*)(Bs + (nf)      * 64 + kcB);
            bf16x8 b1 = *(const bf16x8*)(Bs + (nf + 32) * 64 + kcB);
            acc[0][0] = __builtin_amdgcn_mfma_f32_32x32x16_bf16(a0, b0, acc[0][0], 0, 0, 0);
            acc[0][1] = __builtin_amdgcn_mfma_f32_32x32x16_bf16(a0, b1, acc[0][1], 0, 0, 0);
            acc[1][0] = __builtin_amdgcn_mfma_f32_32x32x16_bf16(a1, b0, acc[1][0], 0, 0, 0);
            acc[1][1] = __builtin_amdgcn_mfma_f32_32x32x16_bf16(a1, b1, acc[1][1], 0, 0, 0);
        }
        __syncthreads();
    }

    if (!isV) {
        float* RS = rowsum + (size_t)bz * LEN;
        float psum[2] = {0.f, 0.f};
        #pragma unroll
        for (int im = 0; im < 2; ++im)
            #pragma unroll
            for (int g4 = 0; g4 < 4; ++g4) {
                const int mb = m0 + wm + im * 32 + g4 * 8 + half * 4;
                #pragma unroll
                for (int jn = 0; jn < 2; ++jn) {
                    const int n = n0 + wn + jn * 32 + col;
                    u16 h0 = f2bf(__expf(acc[im][jn][g4 * 4 + 0] * alpha));
                    u16 h1 = f2bf(__expf(acc[im][jn][g4 * 4 + 1] * alpha));
                    u16 h2 = f2bf(__expf(acc[im][jn][g4 * 4 + 2] * alpha));
                    u16 h3 = f2bf(__expf(acc[im][jn][g4 * 4 + 3] * alpha));
                    psum[jn] += bf2f(h0) + bf2f(h1) + bf2f(h2) + bf2f(h3);
                    *(ushort4*)&O[(size_t)n * LEN + mb] = make_ushort4(h0, h1, h2, h3);
                }
            }
        #pragma unroll
        for (int jn = 0; jn < 2; ++jn) psum[jn] += __shfl_xor(psum[jn], 32, 64);
        if (half == 0) {
            #pragma unroll
            for (int jn = 0; jn < 2; ++jn)
                atomicAdd(&RS[n0 + wn + jn * 32 + col], psum[jn]);
        }
    } else {
        #pragma unroll
        for (int im = 0; im < 2; ++im)
            #pragma unroll
            for (int g4 = 0; g4 < 4; ++g4) {
                const int mb = m0 + wm + im * 32 + g4 * 8 + half * 4;
                #pragma unroll
                for (int jn = 0; jn < 2; ++jn) {
                    const int n = n0 + wn + jn * 32 + col;
                    const float bb = bv[n];
                    ushort4 pk = make_ushort4(f2bf(acc[im][jn][g4 * 4 + 0] + bb),
                                              f2bf(acc[im][jn][g4 * 4 + 1] + bb),
                                              f2bf(acc[im][jn][g4 * 4 + 2] + bb),
                                              f2bf(acc[im][jn][g4 * 4 + 3] + bb));
                    *(ushort4*)&O[(size_t)n * LEN + mb] = pk;
                }
            }
    }
}

// ---------------------------------------------------------------------------
extern "C" void kernel_launch(void* const* d_in, const int* in_sizes, int n_in,
                              void* d_out, int out_size, void* d_ws, size_t ws_size,
                              hipStream_t stream) {
    const float* x    = (const float*)d_in[0];
    const float* gn_w = (const float*)d_in[1];
    const float* gn_b = (const float*)d_in[2];
    const float* wq   = (const float*)d_in[3];
    const float* bq   = (const float*)d_in[4];
    const float* wk   = (const float*)d_in[5];
    const float* bk   = (const float*)d_in[6];
    const float* wv   = (const float*)d_in[7];
    const float* bv   = (const float*)d_in[8];
    const float* wo   = (const float*)d_in[9];
    const float* bo   = (const float*)d_in[10];
    float* out = (float*)d_out;

    char* p = (char*)d_ws;
    const size_t WSZ = (size_t)CH * CH * 2;
    const size_t HSZ = (size_t)BATCH * CH * LEN * 2;
    u16* Wqk = (u16*)p; p += 2 * WSZ;   // rows 0-511 = Wq, 512-1023 = Wk
    u16* Wvb = (u16*)p; p += WSZ;
    u16* Wob = (u16*)p; p += WSZ;
    u16* Ht  = (u16*)p; p += HSZ;   // GN out [b][l][c]; later PV out [b][i][c]
    u16* Qt  = (u16*)p; p += HSZ;   // [b][l][c]
    u16* Kt  = (u16*)p; p += HSZ;   // [b][l][c]
    u16* Vb  = (u16*)p; p += HSZ;   // [b][c][l]
    u16* Sb  = (u16*)p; p += (size_t)BATCH * LEN * LEN * 2;  // exp(scores)
    float* rowsum = (float*)p; p += (size_t)BATCH * LEN * 4; // 16384 f32, zeroed
    float* stats  = (float*)p;      // 2048 f32: S partials | S2 partials

    const long long sH = (long long)LEN * CH;
    const long long sV = (long long)CH * LEN;
    const float scale = 0.04419417382415922f;   // 512^-0.5

    // one pre-pass launch: zero(16) | wconv(1024) | stats partials(1024)
    fused_pre<<<2064, 256, 0, stream>>>(x, wq, wk, wv, wo,
                                        Wqk, Wqk + (size_t)CH * CH, Wvb, Wob,
                                        (float4*)rowsum, stats);
    gn_apply_t<<<dim3(LEN / 64, CH / 64, BATCH), 256, 0, stream>>>(x, stats, gn_w, gn_b, Ht);

    // Q+K fused: A=Wqk (m=o), B=Ht (n=l) -> Qt/Kt[l][o] packed in o
    gemm_bt<EPI_QK><<<dim3(16, 8, 8), 256, 0, stream>>>(
        Wqk, CH, 0, Ht, CH, sH, Qt, Kt, CH, sH, bq, bk, nullptr, 0, nullptr, 0, CH, 0.f);
    // scores (2048 blocks, XCD-remapped) + V (512 blocks) in one launch
    gemm_sv<<<2560, 256, 0, stream>>>(Kt, Qt, Ht, Wvb, Sb, Vb, bv, rowsum, scale);
    // PV: A=Vb (m=c), B=E (n=i) -> Ht[i][c] packed in c, * 1/rowsum[i]
    //     (XCD remap + m-fast inside the kernel for Sb L2 locality)
    gemm_bt<EPI_TNRM><<<dim3(16, 4, 8), 256, 0, stream>>>(
        Vb, LEN, sV, Sb, LEN, (long long)LEN * LEN, Ht, nullptr, CH, sH,
        nullptr, nullptr, nullptr, 0, rowsum, LEN, LEN, 0.f);
    // final: A=Ht (m=l), B=Wo (n=o) -> out[o][l] f32 + bias[o] + x residual
    gemm_bt<EPI_FIN><<<dim3(4, 16, 8), 256, 0, stream>>>(
        Ht, CH, sH, Wob, CH, 0, out, nullptr, LEN, sV, bo, nullptr, x, sV, nullptr, 0, CH, 0.f);
}